// Round 1
// baseline (1444.286 us; speedup 1.0000x reference)
//
#include <hip/hip_runtime.h>
#include <stdint.h>

#define FEAT_STRIDE_I 16
#define A_NUM 9
#define HH 128
#define WW 128
#define NPIX (HH * WW)            // 16384
#define N_ANCH (NPIX * A_NUM)     // 147456
#define B_NUM 8
#define PRE_NMS 6000
#define POST_NMS 300
#define NMS_THRESH_F 0.7f
#define MIN_SIZE_F 16.0f
#define NEG_INF_F -1e30f
#define CAP 8192
#define NBINS 65536

// ---- workspace layout (bytes) ----
#define OFF_HIST  0u                               // 8*65536*4  = 2,097,152
#define OFF_CNT   2097152u                         // 8 cnt + 8 thresh (256B pad)
#define OFF_CAND  2097408u                         // 8*8192*8   =   524,288
#define OFF_KEYS  2621696u                         // 8*147456*4 = 4,718,592
#define OFF_BOXES 7340288u                         // 8*6000*4*4 =   768,000
// total ~8.11 MB

__device__ __forceinline__ unsigned sortable_f32(float f) {
    unsigned u = __float_as_uint(f);
    return (u & 0x80000000u) ? ~u : (u | 0x80000000u);
}

// Decode one anchor's box exactly in the reference's op order.
__device__ __forceinline__ void decode_box(
    int b, int idx,
    const float* __restrict__ deltas, const float* __restrict__ im_info,
    const float* __restrict__ anchors,
    float& x1, float& y1, float& x2, float& y2, bool& valid)
{
    int a   = idx % A_NUM;
    int pix = idx / A_NUM;
    int w   = pix & (WW - 1);
    int h   = pix >> 7;

    float a0 = anchors[a * 4 + 0];
    float a1 = anchors[a * 4 + 1];
    float a2 = anchors[a * 4 + 2];
    float a3 = anchors[a * 4 + 3];

    float aw = __fadd_rn(__fsub_rn(a2, a0), 1.0f);
    float ah = __fadd_rn(__fsub_rn(a3, a1), 1.0f);
    float sx = (float)(w * FEAT_STRIDE_I);
    float sy = (float)(h * FEAT_STRIDE_I);
    // acx = (shift_x + anc0) + 0.5*aw
    float acx = __fadd_rn(__fadd_rn(sx, a0), __fmul_rn(0.5f, aw));
    float acy = __fadd_rn(__fadd_rn(sy, a1), __fmul_rn(0.5f, ah));

    size_t base = ((size_t)b * 36 + 4 * a) * NPIX + pix;
    float dx = deltas[base];
    float dy = deltas[base + NPIX];
    float dw = deltas[base + 2 * (size_t)NPIX];
    float dh = deltas[base + 3 * (size_t)NPIX];

    float pcx = __fadd_rn(__fmul_rn(dx, aw), acx);
    float pcy = __fadd_rn(__fmul_rn(dy, ah), acy);
    float pw  = __fmul_rn(expf(dw), aw);
    float ph  = __fmul_rn(expf(dh), ah);

    float hx = __fmul_rn(0.5f, pw);
    float hy = __fmul_rn(0.5f, ph);
    x1 = __fsub_rn(pcx, hx);
    y1 = __fsub_rn(pcy, hy);
    x2 = __fadd_rn(pcx, hx);
    y2 = __fadd_rn(pcy, hy);

    float im_h = im_info[b * 3 + 0];
    float im_w = im_info[b * 3 + 1];
    float sc   = im_info[b * 3 + 2];
    float wmax = __fsub_rn(im_w, 1.0f);
    float hmax = __fsub_rn(im_h, 1.0f);

    x1 = fminf(fmaxf(x1, 0.0f), wmax);
    y1 = fminf(fmaxf(y1, 0.0f), hmax);
    x2 = fminf(fmaxf(x2, 0.0f), wmax);
    y2 = fminf(fmaxf(y2, 0.0f), hmax);

    float min_sz = __fmul_rn(MIN_SIZE_F, sc);
    valid = (__fadd_rn(__fsub_rn(x2, x1), 1.0f) >= min_sz) &&
            (__fadd_rn(__fsub_rn(y2, y1), 1.0f) >= min_sz);
}

// K1: decode + masked score -> sortable key; histogram on key>>16.
// Thread layout is a-major (lanes consecutive in pix) for coalescing.
__global__ void k_decode_hist(
    const float* __restrict__ scores, const float* __restrict__ deltas,
    const float* __restrict__ im_info, const float* __restrict__ anchors,
    unsigned* __restrict__ hist, unsigned* __restrict__ keys)
{
    int gt = blockIdx.x * blockDim.x + threadIdx.x;
    if (gt >= B_NUM * N_ANCH) return;
    int pix  = gt & (NPIX - 1);
    int rest = gt >> 14;
    int a = rest % A_NUM;
    int b = rest / A_NUM;
    int idx = pix * A_NUM + a;

    float x1, y1, x2, y2; bool valid;
    decode_box(b, idx, deltas, im_info, anchors, x1, y1, x2, y2, valid);

    float s = scores[((size_t)b * 18 + 9 + a) * NPIX + pix];
    if (!valid) s = NEG_INF_F;
    unsigned key = sortable_f32(s);
    keys[gt] = key;
    atomicAdd(&hist[b * NBINS + (key >> 16)], 1u);
}

// K2: per batch find highest bin T with count(bins >= T) >= PRE_NMS.
__global__ void k_thresh(const unsigned* __restrict__ hist,
                         unsigned* __restrict__ thresh)
{
    int b = blockIdx.x;
    const unsigned* h = hist + (size_t)b * NBINS;
    __shared__ unsigned csum[256];
    int t = threadIdx.x;
    unsigned s = 0;
    for (int u = 0; u < 256; ++u) s += h[t * 256 + u];
    csum[t] = s;
    __syncthreads();
    if (t == 0) {
        unsigned acc = 0, T = 0;
        for (int c = 255; c >= 0; --c) {
            if (acc + csum[c] >= PRE_NMS) {
                for (int bin = c * 256 + 255; bin >= c * 256; --bin) {
                    acc += h[bin];
                    if (acc >= PRE_NMS) { T = (unsigned)bin; break; }
                }
                break;
            }
            acc += csum[c];
        }
        thresh[b] = T;
    }
}

// K3: compact candidates (bin >= T) into per-batch list of 64-bit keys.
__global__ void k_compact(
    const unsigned* __restrict__ keys, const unsigned* __restrict__ thresh,
    unsigned* __restrict__ cnt, unsigned long long* __restrict__ cand)
{
    int gt = blockIdx.x * blockDim.x + threadIdx.x;
    if (gt >= B_NUM * N_ANCH) return;
    int pix  = gt & (NPIX - 1);
    int rest = gt >> 14;
    int a = rest % A_NUM;
    int b = rest / A_NUM;

    unsigned key = keys[gt];
    if ((key >> 16) >= thresh[b]) {
        unsigned pos = atomicAdd(&cnt[b], 1u);
        if (pos < CAP) {
            unsigned idx = (unsigned)(pix * A_NUM + a);
            cand[(size_t)b * CAP + pos] =
                ((unsigned long long)key << 32) | (unsigned long long)(0xFFFFFFFFu - idx);
        }
    }
}

// K4: per-batch LDS bitonic sort (descending) of CAP keys; decode top-6000 boxes.
__global__ __launch_bounds__(1024) void k_sort_gather(
    const unsigned long long* __restrict__ cand, const unsigned* __restrict__ cnt,
    const float* __restrict__ deltas, const float* __restrict__ im_info,
    const float* __restrict__ anchors, float* __restrict__ boxes)
{
    __shared__ unsigned long long lk[CAP];
    int b = blockIdx.x;
    int t = threadIdx.x;
    unsigned n = cnt[b];
    if (n > CAP) n = CAP;
    for (int p = t; p < CAP; p += 1024)
        lk[p] = (p < (int)n) ? cand[(size_t)b * CAP + p] : 0ULL;
    __syncthreads();

    for (unsigned k = 2; k <= CAP; k <<= 1) {
        for (unsigned j = k >> 1; j > 0; j >>= 1) {
            for (unsigned i = t; i < CAP; i += 1024) {
                unsigned l = i ^ j;
                if (l > i) {
                    unsigned long long ki = lk[i], kl = lk[l];
                    bool desc = ((i & k) == 0);
                    if (desc ? (ki < kl) : (ki > kl)) { lk[i] = kl; lk[l] = ki; }
                }
            }
            __syncthreads();
        }
    }

    for (int s = t; s < PRE_NMS; s += 1024) {
        unsigned long long key = lk[s];
        int idx = (int)(0xFFFFFFFFu - (unsigned)(key & 0xFFFFFFFFull));
        float x1, y1, x2, y2; bool v;
        decode_box(b, idx, deltas, im_info, anchors, x1, y1, x2, y2, v);
        size_t o = ((size_t)b * PRE_NMS + s) * 4;
        boxes[o + 0] = x1; boxes[o + 1] = y1; boxes[o + 2] = x2; boxes[o + 3] = y2;
    }
}

// K5: per-batch greedy NMS in LDS with early stop at 300 kept; write output.
__global__ __launch_bounds__(1024) void k_nms_out(
    const float* __restrict__ boxes, float* __restrict__ out)
{
    __shared__ float bx1[PRE_NMS], by1[PRE_NMS], bx2[PRE_NMS], by2[PRE_NMS], bar[PRE_NMS];
    __shared__ unsigned rem[(PRE_NMS + 31) / 32];   // 188 words
    __shared__ int kept_idx[POST_NMS];

    int b = blockIdx.x;
    int t = threadIdx.x;

    for (int p = t; p < PRE_NMS; p += 1024) {
        size_t o = ((size_t)b * PRE_NMS + p) * 4;
        float x1 = boxes[o], y1 = boxes[o + 1], x2 = boxes[o + 2], y2 = boxes[o + 3];
        bx1[p] = x1; by1[p] = y1; bx2[p] = x2; by2[p] = y2;
        bar[p] = __fmul_rn(__fadd_rn(__fsub_rn(x2, x1), 1.0f),
                           __fadd_rn(__fsub_rn(y2, y1), 1.0f));
    }
    for (int p = t; p < (PRE_NMS + 31) / 32; p += 1024) rem[p] = 0u;
    __syncthreads();

    int kept = 0;
    for (int i = 0; i < PRE_NMS && kept < POST_NMS; ++i) {
        if (rem[i >> 5] & (1u << (i & 31))) continue;   // uniform across block
        if (t == 0) kept_idx[kept] = i;
        float xi1 = bx1[i], yi1 = by1[i], xi2 = bx2[i], yi2 = by2[i], ai = bar[i];
        for (int j = i + 1 + t; j < PRE_NMS; j += 1024) {
            float xx1 = fmaxf(xi1, bx1[j]);
            float yy1 = fmaxf(yi1, by1[j]);
            float xx2 = fminf(xi2, bx2[j]);
            float yy2 = fminf(yi2, by2[j]);
            float iw = fmaxf(0.0f, __fadd_rn(__fsub_rn(xx2, xx1), 1.0f));
            float ih = fmaxf(0.0f, __fadd_rn(__fsub_rn(yy2, yy1), 1.0f));
            float inter = __fmul_rn(iw, ih);
            if (inter > 0.0f) {
                float uni = __fsub_rn(__fadd_rn(ai, bar[j]), inter);
                float iou = __fdiv_rn(inter, uni);
                if (iou > NMS_THRESH_F) atomicOr(&rem[j >> 5], 1u << (j & 31));
            }
        }
        ++kept;
        __syncthreads();
    }

    for (int k = t; k < POST_NMS; k += 1024) {
        size_t o = ((size_t)b * POST_NMS + k) * 5;
        out[o] = (float)b;
        if (k < kept) {
            int ii = kept_idx[k];
            out[o + 1] = bx1[ii]; out[o + 2] = by1[ii];
            out[o + 3] = bx2[ii]; out[o + 4] = by2[ii];
        } else {
            out[o + 1] = 0.0f; out[o + 2] = 0.0f; out[o + 3] = 0.0f; out[o + 4] = 0.0f;
        }
    }
}

extern "C" void kernel_launch(void* const* d_in, const int* in_sizes, int n_in,
                              void* d_out, int out_size, void* d_ws, size_t ws_size,
                              hipStream_t stream)
{
    const float* scores  = (const float*)d_in[0];
    const float* deltas  = (const float*)d_in[1];
    const float* im_info = (const float*)d_in[2];
    const float* anchors = (const float*)d_in[3];
    float* out = (float*)d_out;
    char* ws = (char*)d_ws;

    unsigned* hist             = (unsigned*)(ws + OFF_HIST);
    unsigned* cnt              = (unsigned*)(ws + OFF_CNT);
    unsigned* thresh           = cnt + 8;
    unsigned long long* cand   = (unsigned long long*)(ws + OFF_CAND);
    unsigned* keys             = (unsigned*)(ws + OFF_KEYS);
    float* boxes               = (float*)(ws + OFF_BOXES);

    // zero histograms + counters (deterministic per call)
    hipMemsetAsync(ws, 0, OFF_CAND, stream);

    int total = B_NUM * N_ANCH;
    int blk = 256;
    k_decode_hist<<<(total + blk - 1) / blk, blk, 0, stream>>>(
        scores, deltas, im_info, anchors, hist, keys);
    k_thresh<<<B_NUM, 256, 0, stream>>>(hist, thresh);
    k_compact<<<(total + blk - 1) / blk, blk, 0, stream>>>(keys, thresh, cnt, cand);
    k_sort_gather<<<B_NUM, 1024, 0, stream>>>(cand, cnt, deltas, im_info, anchors, boxes);
    k_nms_out<<<B_NUM, 1024, 0, stream>>>(boxes, out);
}

// Round 3
// 875.308 us; speedup vs baseline: 1.6500x; 1.6500x over previous
//
#include <hip/hip_runtime.h>
#include <stdint.h>

#define FEAT_STRIDE_I 16
#define A_NUM 9
#define HH 128
#define WW 128
#define NPIX (HH * WW)            // 16384
#define N_ANCH (NPIX * A_NUM)     // 147456
#define B_NUM 8
#define PRE_NMS 6000
#define POST_NMS 300
#define NMS_THRESH_F 0.7f
#define MIN_SIZE_F 16.0f
#define NEG_INF_F -1e30f
#define CAP 8192
#define NBINS 65536

// ---- workspace layout (bytes) ----
#define OFF_HIST  0u                               // 8*65536*4  = 2,097,152
#define OFF_CNT   2097152u                         // 8 cnt + 8 thresh (256B pad)
#define OFF_CAND  2097408u                         // 8*8192*8   =   524,288
#define OFF_KEYS  2621696u                         // 8*147456*4 = 4,718,592
#define OFF_BOXES 7340288u                         // 8*6000*4*4 =   768,000
// total ~8.11 MB

__device__ __forceinline__ unsigned sortable_f32(float f) {
    unsigned u = __float_as_uint(f);
    return (u & 0x80000000u) ? ~u : (u | 0x80000000u);
}

// Decode one anchor's box exactly in the reference's op order.
__device__ __forceinline__ void decode_box(
    int b, int idx,
    const float* __restrict__ deltas, const float* __restrict__ im_info,
    const float* __restrict__ anchors,
    float& x1, float& y1, float& x2, float& y2, bool& valid)
{
    int a   = idx % A_NUM;
    int pix = idx / A_NUM;
    int w   = pix & (WW - 1);
    int h   = pix >> 7;

    float a0 = anchors[a * 4 + 0];
    float a1 = anchors[a * 4 + 1];
    float a2 = anchors[a * 4 + 2];
    float a3 = anchors[a * 4 + 3];

    float aw = __fadd_rn(__fsub_rn(a2, a0), 1.0f);
    float ah = __fadd_rn(__fsub_rn(a3, a1), 1.0f);
    float sx = (float)(w * FEAT_STRIDE_I);
    float sy = (float)(h * FEAT_STRIDE_I);
    // acx = (shift_x + anc0) + 0.5*aw
    float acx = __fadd_rn(__fadd_rn(sx, a0), __fmul_rn(0.5f, aw));
    float acy = __fadd_rn(__fadd_rn(sy, a1), __fmul_rn(0.5f, ah));

    size_t base = ((size_t)b * 36 + 4 * a) * NPIX + pix;
    float dx = deltas[base];
    float dy = deltas[base + NPIX];
    float dw = deltas[base + 2 * (size_t)NPIX];
    float dh = deltas[base + 3 * (size_t)NPIX];

    float pcx = __fadd_rn(__fmul_rn(dx, aw), acx);
    float pcy = __fadd_rn(__fmul_rn(dy, ah), acy);
    float pw  = __fmul_rn(expf(dw), aw);
    float ph  = __fmul_rn(expf(dh), ah);

    float hx = __fmul_rn(0.5f, pw);
    float hy = __fmul_rn(0.5f, ph);
    x1 = __fsub_rn(pcx, hx);
    y1 = __fsub_rn(pcy, hy);
    x2 = __fadd_rn(pcx, hx);
    y2 = __fadd_rn(pcy, hy);

    float im_h = im_info[b * 3 + 0];
    float im_w = im_info[b * 3 + 1];
    float sc   = im_info[b * 3 + 2];
    float wmax = __fsub_rn(im_w, 1.0f);
    float hmax = __fsub_rn(im_h, 1.0f);

    x1 = fminf(fmaxf(x1, 0.0f), wmax);
    y1 = fminf(fmaxf(y1, 0.0f), hmax);
    x2 = fminf(fmaxf(x2, 0.0f), wmax);
    y2 = fminf(fmaxf(y2, 0.0f), hmax);

    float min_sz = __fmul_rn(MIN_SIZE_F, sc);
    valid = (__fadd_rn(__fsub_rn(x2, x1), 1.0f) >= min_sz) &&
            (__fadd_rn(__fsub_rn(y2, y1), 1.0f) >= min_sz);
}

// K1: decode + masked score -> sortable key; histogram on key>>16.
// Thread layout is a-major (lanes consecutive in pix) for coalescing.
__global__ void k_decode_hist(
    const float* __restrict__ scores, const float* __restrict__ deltas,
    const float* __restrict__ im_info, const float* __restrict__ anchors,
    unsigned* __restrict__ hist, unsigned* __restrict__ keys)
{
    int gt = blockIdx.x * blockDim.x + threadIdx.x;
    if (gt >= B_NUM * N_ANCH) return;
    int pix  = gt & (NPIX - 1);
    int rest = gt >> 14;
    int a = rest % A_NUM;
    int b = rest / A_NUM;
    int idx = pix * A_NUM + a;

    float x1, y1, x2, y2; bool valid;
    decode_box(b, idx, deltas, im_info, anchors, x1, y1, x2, y2, valid);

    float s = scores[((size_t)b * 18 + 9 + a) * NPIX + pix];
    if (!valid) s = NEG_INF_F;
    unsigned key = sortable_f32(s);
    keys[gt] = key;
    atomicAdd(&hist[b * NBINS + (key >> 16)], 1u);
}

// K2: per batch find highest bin T with count(bins >= T) >= PRE_NMS.
__global__ void k_thresh(const unsigned* __restrict__ hist,
                         unsigned* __restrict__ thresh)
{
    int b = blockIdx.x;
    const unsigned* h = hist + (size_t)b * NBINS;
    __shared__ unsigned csum[256];
    int t = threadIdx.x;
    unsigned s = 0;
    for (int u = 0; u < 256; ++u) s += h[t * 256 + u];
    csum[t] = s;
    __syncthreads();
    if (t == 0) {
        unsigned acc = 0, T = 0;
        for (int c = 255; c >= 0; --c) {
            if (acc + csum[c] >= PRE_NMS) {
                for (int bin = c * 256 + 255; bin >= c * 256; --bin) {
                    acc += h[bin];
                    if (acc >= PRE_NMS) { T = (unsigned)bin; break; }
                }
                break;
            }
            acc += csum[c];
        }
        thresh[b] = T;
    }
}

// K3: compact candidates (bin >= T) into per-batch list of 64-bit keys.
// Block-aggregated: one atomicAdd per block (each block lies in one batch:
// N_ANCH = 576*256 exactly). Order within cand[] is nondeterministic but the
// full 64-bit sort in K4 restores deterministic order (score, then ~idx).
__global__ void k_compact(
    const unsigned* __restrict__ keys, const unsigned* __restrict__ thresh,
    unsigned* __restrict__ cnt, unsigned long long* __restrict__ cand)
{
    int gt = blockIdx.x * blockDim.x + threadIdx.x;
    int pix  = gt & (NPIX - 1);
    int rest = gt >> 14;
    int a = rest % A_NUM;
    int b = rest / A_NUM;

    unsigned key = keys[gt];
    bool pass = (key >> 16) >= thresh[b];

    unsigned long long mask = __ballot(pass);
    int lane = threadIdx.x & 63;
    int wid  = threadIdx.x >> 6;
    unsigned wrank = (unsigned)__popcll(mask & ((1ULL << lane) - 1ULL));
    unsigned wtot  = (unsigned)__popcll(mask);

    __shared__ unsigned wbase[4];
    __shared__ unsigned blockbase;
    if (lane == 0) wbase[wid] = wtot;
    __syncthreads();
    if (threadIdx.x == 0) {
        unsigned s0 = wbase[0], s1 = wbase[1], s2 = wbase[2], s3 = wbase[3];
        unsigned tot = s0 + s1 + s2 + s3;
        blockbase = tot ? atomicAdd(&cnt[b], tot) : 0u;
        wbase[0] = 0; wbase[1] = s0; wbase[2] = s0 + s1; wbase[3] = s0 + s1 + s2;
    }
    __syncthreads();

    if (pass) {
        unsigned pos = blockbase + wbase[wid] + wrank;
        if (pos < CAP) {
            unsigned idx = (unsigned)(pix * A_NUM + a);
            cand[(size_t)b * CAP + pos] =
                ((unsigned long long)key << 32) | (unsigned long long)(0xFFFFFFFFu - idx);
        }
    }
}

// K4: per-batch LDS bitonic sort (descending) of CAP keys; decode top-6000 boxes.
__global__ __launch_bounds__(1024) void k_sort_gather(
    const unsigned long long* __restrict__ cand, const unsigned* __restrict__ cnt,
    const float* __restrict__ deltas, const float* __restrict__ im_info,
    const float* __restrict__ anchors, float* __restrict__ boxes)
{
    __shared__ unsigned long long lk[CAP];
    int b = blockIdx.x;
    int t = threadIdx.x;
    unsigned n = cnt[b];
    if (n > CAP) n = CAP;
    for (int p = t; p < CAP; p += 1024)
        lk[p] = (p < (int)n) ? cand[(size_t)b * CAP + p] : 0ULL;
    __syncthreads();

    for (unsigned k = 2; k <= CAP; k <<= 1) {
        for (unsigned j = k >> 1; j > 0; j >>= 1) {
            for (unsigned i = t; i < CAP; i += 1024) {
                unsigned l = i ^ j;
                if (l > i) {
                    unsigned long long ki = lk[i], kl = lk[l];
                    bool desc = ((i & k) == 0);
                    if (desc ? (ki < kl) : (ki > kl)) { lk[i] = kl; lk[l] = ki; }
                }
            }
            __syncthreads();
        }
    }

    for (int s = t; s < PRE_NMS; s += 1024) {
        unsigned long long key = lk[s];
        int idx = (int)(0xFFFFFFFFu - (unsigned)(key & 0xFFFFFFFFull));
        float x1, y1, x2, y2; bool v;
        decode_box(b, idx, deltas, im_info, anchors, x1, y1, x2, y2, v);
        size_t o = ((size_t)b * PRE_NMS + s) * 4;
        boxes[o + 0] = x1; boxes[o + 1] = y1; boxes[o + 2] = x2; boxes[o + 3] = y2;
    }
}

// K5: per-batch greedy NMS in LDS with early stop at 300 kept; write output.
__global__ __launch_bounds__(1024) void k_nms_out(
    const float* __restrict__ boxes, float* __restrict__ out)
{
    __shared__ float bx1[PRE_NMS], by1[PRE_NMS], bx2[PRE_NMS], by2[PRE_NMS], bar[PRE_NMS];
    __shared__ unsigned rem[(PRE_NMS + 31) / 32];   // 188 words
    __shared__ int kept_idx[POST_NMS];

    int b = blockIdx.x;
    int t = threadIdx.x;

    for (int p = t; p < PRE_NMS; p += 1024) {
        size_t o = ((size_t)b * PRE_NMS + p) * 4;
        float x1 = boxes[o], y1 = boxes[o + 1], x2 = boxes[o + 2], y2 = boxes[o + 3];
        bx1[p] = x1; by1[p] = y1; bx2[p] = x2; by2[p] = y2;
        bar[p] = __fmul_rn(__fadd_rn(__fsub_rn(x2, x1), 1.0f),
                           __fadd_rn(__fsub_rn(y2, y1), 1.0f));
    }
    for (int p = t; p < (PRE_NMS + 31) / 32; p += 1024) rem[p] = 0u;
    __syncthreads();

    int kept = 0;
    for (int i = 0; i < PRE_NMS && kept < POST_NMS; ++i) {
        if (rem[i >> 5] & (1u << (i & 31))) continue;   // uniform across block
        if (t == 0) kept_idx[kept] = i;
        float xi1 = bx1[i], yi1 = by1[i], xi2 = bx2[i], yi2 = by2[i], ai = bar[i];
        for (int j = i + 1 + t; j < PRE_NMS; j += 1024) {
            float xx1 = fmaxf(xi1, bx1[j]);
            float yy1 = fmaxf(yi1, by1[j]);
            float xx2 = fminf(xi2, bx2[j]);
            float yy2 = fminf(yi2, by2[j]);
            float iw = fmaxf(0.0f, __fadd_rn(__fsub_rn(xx2, xx1), 1.0f));
            float ih = fmaxf(0.0f, __fadd_rn(__fsub_rn(yy2, yy1), 1.0f));
            float inter = __fmul_rn(iw, ih);
            if (inter > 0.0f) {
                float uni = __fsub_rn(__fadd_rn(ai, bar[j]), inter);
                float iou = __fdiv_rn(inter, uni);
                if (iou > NMS_THRESH_F) atomicOr(&rem[j >> 5], 1u << (j & 31));
            }
        }
        ++kept;
        __syncthreads();
    }

    for (int k = t; k < POST_NMS; k += 1024) {
        size_t o = ((size_t)b * POST_NMS + k) * 5;
        out[o] = (float)b;
        if (k < kept) {
            int ii = kept_idx[k];
            out[o + 1] = bx1[ii]; out[o + 2] = by1[ii];
            out[o + 3] = bx2[ii]; out[o + 4] = by2[ii];
        } else {
            out[o + 1] = 0.0f; out[o + 2] = 0.0f; out[o + 3] = 0.0f; out[o + 4] = 0.0f;
        }
    }
}

extern "C" void kernel_launch(void* const* d_in, const int* in_sizes, int n_in,
                              void* d_out, int out_size, void* d_ws, size_t ws_size,
                              hipStream_t stream)
{
    const float* scores  = (const float*)d_in[0];
    const float* deltas  = (const float*)d_in[1];
    const float* im_info = (const float*)d_in[2];
    const float* anchors = (const float*)d_in[3];
    float* out = (float*)d_out;
    char* ws = (char*)d_ws;

    unsigned* hist             = (unsigned*)(ws + OFF_HIST);
    unsigned* cnt              = (unsigned*)(ws + OFF_CNT);
    unsigned* thresh           = cnt + 8;
    unsigned long long* cand   = (unsigned long long*)(ws + OFF_CAND);
    unsigned* keys             = (unsigned*)(ws + OFF_KEYS);
    float* boxes               = (float*)(ws + OFF_BOXES);

    // zero histograms + counters (deterministic per call)
    hipMemsetAsync(ws, 0, OFF_CAND, stream);

    int total = B_NUM * N_ANCH;
    int blk = 256;
    k_decode_hist<<<(total + blk - 1) / blk, blk, 0, stream>>>(
        scores, deltas, im_info, anchors, hist, keys);
    k_thresh<<<B_NUM, 256, 0, stream>>>(hist, thresh);
    k_compact<<<(total + blk - 1) / blk, blk, 0, stream>>>(keys, thresh, cnt, cand);
    k_sort_gather<<<B_NUM, 1024, 0, stream>>>(cand, cnt, deltas, im_info, anchors, boxes);
    k_nms_out<<<B_NUM, 1024, 0, stream>>>(boxes, out);
}

// Round 4
// 577.440 us; speedup vs baseline: 2.5012x; 1.5158x over previous
//
#include <hip/hip_runtime.h>
#include <stdint.h>

#define FEAT_STRIDE_I 16
#define A_NUM 9
#define HH 128
#define WW 128
#define NPIX (HH * WW)            // 16384
#define N_ANCH (NPIX * A_NUM)     // 147456
#define B_NUM 8
#define PRE_NMS 6000
#define POST_NMS 300
#define NMS_THRESH_F 0.7f
#define MIN_SIZE_F 16.0f
#define NEG_INF_F -1e30f
#define CAP 8192
#define NBINS 65536

#define MWORDS 188                 // ceil(6000/32)
#define RT_TILES 94                // ceil(6000/64)
#define TRI_TILES 4465             // RT_TILES*(RT_TILES+1)/2

// ---- workspace layout (bytes) ----
#define OFF_HIST  0u               // 8*65536*4  = 2,097,152
#define OFF_CNT   2097152u         // 8 cnt + 8 thresh
#define OFF_CAND  2097408u         // 8*8192*8   =   524,288
#define OFF_KEYS  2621696u         // 8*147456*4 = 4,718,592
#define OFF_BOXES 7340288u         // 8*6000*4*4 =   768,000
#define OFF_KEPT  8108288u         // 8*304*4    =     9,728
#define OFF_MASK  8118272u         // 8*6000*188*4 = 36,096,000
#define MASK_BYTES ((size_t)B_NUM * PRE_NMS * MWORDS * 4)

__device__ __forceinline__ unsigned sortable_f32(float f) {
    unsigned u = __float_as_uint(f);
    return (u & 0x80000000u) ? ~u : (u | 0x80000000u);
}

// Decode one anchor's box exactly in the reference's op order.
__device__ __forceinline__ void decode_box(
    int b, int idx,
    const float* __restrict__ deltas, const float* __restrict__ im_info,
    const float* __restrict__ anchors,
    float& x1, float& y1, float& x2, float& y2, bool& valid)
{
    int a   = idx % A_NUM;
    int pix = idx / A_NUM;
    int w   = pix & (WW - 1);
    int h   = pix >> 7;

    float a0 = anchors[a * 4 + 0];
    float a1 = anchors[a * 4 + 1];
    float a2 = anchors[a * 4 + 2];
    float a3 = anchors[a * 4 + 3];

    float aw = __fadd_rn(__fsub_rn(a2, a0), 1.0f);
    float ah = __fadd_rn(__fsub_rn(a3, a1), 1.0f);
    float sx = (float)(w * FEAT_STRIDE_I);
    float sy = (float)(h * FEAT_STRIDE_I);
    float acx = __fadd_rn(__fadd_rn(sx, a0), __fmul_rn(0.5f, aw));
    float acy = __fadd_rn(__fadd_rn(sy, a1), __fmul_rn(0.5f, ah));

    size_t base = ((size_t)b * 36 + 4 * a) * NPIX + pix;
    float dx = deltas[base];
    float dy = deltas[base + NPIX];
    float dw = deltas[base + 2 * (size_t)NPIX];
    float dh = deltas[base + 3 * (size_t)NPIX];

    float pcx = __fadd_rn(__fmul_rn(dx, aw), acx);
    float pcy = __fadd_rn(__fmul_rn(dy, ah), acy);
    float pw  = __fmul_rn(expf(dw), aw);
    float ph  = __fmul_rn(expf(dh), ah);

    float hx = __fmul_rn(0.5f, pw);
    float hy = __fmul_rn(0.5f, ph);
    x1 = __fsub_rn(pcx, hx);
    y1 = __fsub_rn(pcy, hy);
    x2 = __fadd_rn(pcx, hx);
    y2 = __fadd_rn(pcy, hy);

    float im_h = im_info[b * 3 + 0];
    float im_w = im_info[b * 3 + 1];
    float sc   = im_info[b * 3 + 2];
    float wmax = __fsub_rn(im_w, 1.0f);
    float hmax = __fsub_rn(im_h, 1.0f);

    x1 = fminf(fmaxf(x1, 0.0f), wmax);
    y1 = fminf(fmaxf(y1, 0.0f), hmax);
    x2 = fminf(fmaxf(x2, 0.0f), wmax);
    y2 = fminf(fmaxf(y2, 0.0f), hmax);

    float min_sz = __fmul_rn(MIN_SIZE_F, sc);
    valid = (__fadd_rn(__fsub_rn(x2, x1), 1.0f) >= min_sz) &&
            (__fadd_rn(__fsub_rn(y2, y1), 1.0f) >= min_sz);
}

// K1: decode + masked score -> sortable key; histogram on key>>16.
__global__ void k_decode_hist(
    const float* __restrict__ scores, const float* __restrict__ deltas,
    const float* __restrict__ im_info, const float* __restrict__ anchors,
    unsigned* __restrict__ hist, unsigned* __restrict__ keys)
{
    int gt = blockIdx.x * blockDim.x + threadIdx.x;
    if (gt >= B_NUM * N_ANCH) return;
    int pix  = gt & (NPIX - 1);
    int rest = gt >> 14;
    int a = rest % A_NUM;
    int b = rest / A_NUM;
    int idx = pix * A_NUM + a;

    float x1, y1, x2, y2; bool valid;
    decode_box(b, idx, deltas, im_info, anchors, x1, y1, x2, y2, valid);

    float s = scores[((size_t)b * 18 + 9 + a) * NPIX + pix];
    if (!valid) s = NEG_INF_F;
    unsigned key = sortable_f32(s);
    keys[gt] = key;
    atomicAdd(&hist[b * NBINS + (key >> 16)], 1u);
}

// K2: per batch find highest bin T with count(bins >= T) >= PRE_NMS.
__global__ void k_thresh(const unsigned* __restrict__ hist,
                         unsigned* __restrict__ thresh)
{
    int b = blockIdx.x;
    const unsigned* h = hist + (size_t)b * NBINS;
    __shared__ unsigned csum[256];
    int t = threadIdx.x;
    unsigned s = 0;
    for (int u = 0; u < 256; ++u) s += h[t * 256 + u];
    csum[t] = s;
    __syncthreads();
    if (t == 0) {
        unsigned acc = 0, T = 0;
        for (int c = 255; c >= 0; --c) {
            if (acc + csum[c] >= PRE_NMS) {
                for (int bin = c * 256 + 255; bin >= c * 256; --bin) {
                    acc += h[bin];
                    if (acc >= PRE_NMS) { T = (unsigned)bin; break; }
                }
                break;
            }
            acc += csum[c];
        }
        thresh[b] = T;
    }
}

// K3: block-aggregated compaction (one global atomic per block).
__global__ void k_compact(
    const unsigned* __restrict__ keys, const unsigned* __restrict__ thresh,
    unsigned* __restrict__ cnt, unsigned long long* __restrict__ cand)
{
    int gt = blockIdx.x * blockDim.x + threadIdx.x;
    int pix  = gt & (NPIX - 1);
    int rest = gt >> 14;
    int a = rest % A_NUM;
    int b = rest / A_NUM;

    unsigned key = keys[gt];
    bool pass = (key >> 16) >= thresh[b];

    unsigned long long mask = __ballot(pass);
    int lane = threadIdx.x & 63;
    int wid  = threadIdx.x >> 6;
    unsigned wrank = (unsigned)__popcll(mask & ((1ULL << lane) - 1ULL));
    unsigned wtot  = (unsigned)__popcll(mask);

    __shared__ unsigned wbase[4];
    __shared__ unsigned blockbase;
    if (lane == 0) wbase[wid] = wtot;
    __syncthreads();
    if (threadIdx.x == 0) {
        unsigned s0 = wbase[0], s1 = wbase[1], s2 = wbase[2], s3 = wbase[3];
        unsigned tot = s0 + s1 + s2 + s3;
        blockbase = tot ? atomicAdd(&cnt[b], tot) : 0u;
        wbase[0] = 0; wbase[1] = s0; wbase[2] = s0 + s1; wbase[3] = s0 + s1 + s2;
    }
    __syncthreads();

    if (pass) {
        unsigned pos = blockbase + wbase[wid] + wrank;
        if (pos < CAP) {
            unsigned idx = (unsigned)(pix * A_NUM + a);
            cand[(size_t)b * CAP + pos] =
                ((unsigned long long)key << 32) | (unsigned long long)(0xFFFFFFFFu - idx);
        }
    }
}

// K4: per-batch LDS bitonic sort (descending) of CAP keys; decode top-6000 boxes.
__global__ __launch_bounds__(1024) void k_sort_gather(
    const unsigned long long* __restrict__ cand, const unsigned* __restrict__ cnt,
    const float* __restrict__ deltas, const float* __restrict__ im_info,
    const float* __restrict__ anchors, float* __restrict__ boxes)
{
    __shared__ unsigned long long lk[CAP];
    int b = blockIdx.x;
    int t = threadIdx.x;
    unsigned n = cnt[b];
    if (n > CAP) n = CAP;
    for (int p = t; p < CAP; p += 1024)
        lk[p] = (p < (int)n) ? cand[(size_t)b * CAP + p] : 0ULL;
    __syncthreads();

    for (unsigned k = 2; k <= CAP; k <<= 1) {
        for (unsigned j = k >> 1; j > 0; j >>= 1) {
            for (unsigned i = t; i < CAP; i += 1024) {
                unsigned l = i ^ j;
                if (l > i) {
                    unsigned long long ki = lk[i], kl = lk[l];
                    bool desc = ((i & k) == 0);
                    if (desc ? (ki < kl) : (ki > kl)) { lk[i] = kl; lk[l] = ki; }
                }
            }
            __syncthreads();
        }
    }

    for (int s = t; s < PRE_NMS; s += 1024) {
        unsigned long long key = lk[s];
        int idx = (int)(0xFFFFFFFFu - (unsigned)(key & 0xFFFFFFFFull));
        float x1, y1, x2, y2; bool v;
        decode_box(b, idx, deltas, im_info, anchors, x1, y1, x2, y2, v);
        size_t o = ((size_t)b * PRE_NMS + s) * 4;
        boxes[o + 0] = x1; boxes[o + 1] = y1; boxes[o + 2] = x2; boxes[o + 3] = y2;
    }
}

// K5a: upper-triangular IoU suppression bitmask. One wave per (batch, row-tile,
// col-tile) with col-tile >= row-tile. Lower-triangle words are never written;
// garbage there only sets bits for j<i, which are already decided at scan time.
__global__ __launch_bounds__(64) void k_iou_mask(
    const float* __restrict__ boxes, unsigned* __restrict__ mask)
{
    int bid = blockIdx.x;
    int b = bid / TRI_TILES;
    int t = bid - b * TRI_TILES;
    float disc = (float)((2 * RT_TILES + 1) * (2 * RT_TILES + 1) - 8 * t);
    int R = (int)((2.0f * RT_TILES + 1.0f - sqrtf(disc)) * 0.5f);
    while (R > 0 && (R * RT_TILES - (R * (R - 1)) / 2) > t) --R;
    while (((R + 1) * RT_TILES - ((R + 1) * R) / 2) <= t) ++R;
    int C = R + (t - (R * RT_TILES - (R * (R - 1)) / 2));

    int lane = threadIdx.x;
    const float* Bb = boxes + (size_t)b * PRE_NMS * 4;

    int j = C * 64 + lane;
    float jx1 = 0.f, jy1 = 0.f, jx2 = -1.f, jy2 = -1.f, ja = 0.f;
    bool jv = (j < PRE_NMS);
    if (jv) {
        float4 v = *(const float4*)(Bb + 4 * (size_t)j);
        jx1 = v.x; jy1 = v.y; jx2 = v.z; jy2 = v.w;
        ja = __fmul_rn(__fadd_rn(__fsub_rn(jx2, jx1), 1.0f),
                       __fadd_rn(__fsub_rn(jy2, jy1), 1.0f));
    }

    __shared__ float4 rb4[64];
    __shared__ float rba[64];
    int il = R * 64 + lane;
    if (il < PRE_NMS) {
        float4 v = *(const float4*)(Bb + 4 * (size_t)il);
        rb4[lane] = v;
        rba[lane] = __fmul_rn(__fadd_rn(__fsub_rn(v.z, v.x), 1.0f),
                              __fadd_rn(__fsub_rn(v.w, v.y), 1.0f));
    }
    __syncthreads();

    unsigned* Mb = mask + (size_t)b * PRE_NMS * MWORDS;
    int imax = min(64, PRE_NMS - R * 64);
    for (int ri = 0; ri < imax; ++ri) {
        int i = R * 64 + ri;
        float4 bi = rb4[ri];
        float ia = rba[ri];
        float xx1 = fmaxf(bi.x, jx1);
        float yy1 = fmaxf(bi.y, jy1);
        float xx2 = fminf(bi.z, jx2);
        float yy2 = fminf(bi.w, jy2);
        float iw = fmaxf(0.0f, __fadd_rn(__fsub_rn(xx2, xx1), 1.0f));
        float ih = fmaxf(0.0f, __fadd_rn(__fsub_rn(yy2, yy1), 1.0f));
        float inter = __fmul_rn(iw, ih);
        float uni = __fsub_rn(__fadd_rn(ia, ja), inter);
        float iou = __fdiv_rn(inter, uni);
        bool pass = jv && (j > i) && (inter > 0.0f) && (iou > NMS_THRESH_F);
        unsigned long long m = __ballot(pass);
        if (lane == 0)
            *(unsigned long long*)(Mb + (size_t)i * MWORDS + 2 * C) = m;
    }
}

// K5b: serial greedy scan over the bitmask, one wave per batch. Rows are
// prefetched unconditionally 8 deep (static register slots).
__global__ __launch_bounds__(64) void k_nms_scan(
    const unsigned* __restrict__ mask, unsigned* __restrict__ keptbuf)
{
    const int b = blockIdx.x;
    const int l = threadIdx.x;
    __shared__ unsigned supp[MWORDS];
    __shared__ int klist[POST_NMS];
    supp[l] = 0u;
    supp[l + 64] = 0u;
    if (l < MWORDS - 128) supp[l + 128] = 0u;
    __syncthreads();

    const unsigned* __restrict__ M = mask + (size_t)b * PRE_NMS * MWORDS;
    int kept = 0;
    unsigned curw = 0; int curwi = -1;

#define LOADROW(p0, p1, p2, i) { \
        const unsigned* _r = M + (size_t)(((i) < PRE_NMS) ? (i) : (PRE_NMS - 1)) * MWORDS; \
        p0 = _r[l]; p1 = _r[l + 64]; p2 = (l < MWORDS - 128) ? _r[l + 128] : 0u; }

#define STEP(i, p0, p1, p2) { \
        if (kept < POST_NMS) { \
            int _wi = (i) >> 5; \
            if (_wi != curwi) { curw = supp[_wi]; curwi = _wi; } \
            if (!((curw >> ((i) & 31)) & 1u)) { \
                if (l == 0) klist[kept] = (i); \
                supp[l]      |= p0; \
                supp[l + 64] |= p1; \
                if (l < MWORDS - 128) supp[l + 128] |= p2; \
                ++kept; curwi = -1; \
            } \
        } }

    unsigned a0, a1, a2, c0, c1, c2, d0, d1, d2, e0, e1, e2;
    unsigned f0, f1, f2, g0, g1, g2, h0, h1, h2, q0, q1, q2;
    LOADROW(a0, a1, a2, 0) LOADROW(c0, c1, c2, 1)
    LOADROW(d0, d1, d2, 2) LOADROW(e0, e1, e2, 3)
    LOADROW(f0, f1, f2, 4) LOADROW(g0, g1, g2, 5)
    LOADROW(h0, h1, h2, 6) LOADROW(q0, q1, q2, 7)

    for (int i = 0; i < PRE_NMS && kept < POST_NMS; i += 8) {
        STEP(i + 0, a0, a1, a2) LOADROW(a0, a1, a2, i + 8)
        STEP(i + 1, c0, c1, c2) LOADROW(c0, c1, c2, i + 9)
        STEP(i + 2, d0, d1, d2) LOADROW(d0, d1, d2, i + 10)
        STEP(i + 3, e0, e1, e2) LOADROW(e0, e1, e2, i + 11)
        STEP(i + 4, f0, f1, f2) LOADROW(f0, f1, f2, i + 12)
        STEP(i + 5, g0, g1, g2) LOADROW(g0, g1, g2, i + 13)
        STEP(i + 6, h0, h1, h2) LOADROW(h0, h1, h2, i + 14)
        STEP(i + 7, q0, q1, q2) LOADROW(q0, q1, q2, i + 15)
    }
    __syncthreads();
    if (l == 0) keptbuf[b * 304] = (unsigned)kept;
    for (int k = l; k < POST_NMS; k += 64)
        keptbuf[b * 304 + 1 + k] = (k < (int)kept) ? (unsigned)klist[k] : 0u;
#undef LOADROW
#undef STEP
}

// K5c: write output from kept list.
__global__ void k_nms_gather(const float* __restrict__ boxes,
                             const unsigned* __restrict__ keptbuf,
                             float* __restrict__ out)
{
    int b = blockIdx.x;
    int t = threadIdx.x;
    unsigned kept = keptbuf[b * 304];
    if (t < POST_NMS) {
        size_t o = ((size_t)b * POST_NMS + t) * 5;
        float x1 = 0.f, y1 = 0.f, x2 = 0.f, y2 = 0.f;
        if (t < (int)kept) {
            unsigned idx = keptbuf[b * 304 + 1 + t];
            const float4 v = *(const float4*)(boxes + ((size_t)b * PRE_NMS + idx) * 4);
            x1 = v.x; y1 = v.y; x2 = v.z; y2 = v.w;
        }
        out[o + 0] = (float)b;
        out[o + 1] = x1; out[o + 2] = y1; out[o + 3] = x2; out[o + 4] = y2;
    }
}

// Fallback NMS (used only if ws_size is too small for the bitmask).
__global__ __launch_bounds__(1024) void k_nms_out(
    const float* __restrict__ boxes, float* __restrict__ out)
{
    __shared__ float bx1[PRE_NMS], by1[PRE_NMS], bx2[PRE_NMS], by2[PRE_NMS], bar[PRE_NMS];
    __shared__ unsigned rem[(PRE_NMS + 31) / 32];
    __shared__ int kept_idx[POST_NMS];

    int b = blockIdx.x;
    int t = threadIdx.x;

    for (int p = t; p < PRE_NMS; p += 1024) {
        size_t o = ((size_t)b * PRE_NMS + p) * 4;
        float x1 = boxes[o], y1 = boxes[o + 1], x2 = boxes[o + 2], y2 = boxes[o + 3];
        bx1[p] = x1; by1[p] = y1; bx2[p] = x2; by2[p] = y2;
        bar[p] = __fmul_rn(__fadd_rn(__fsub_rn(x2, x1), 1.0f),
                           __fadd_rn(__fsub_rn(y2, y1), 1.0f));
    }
    for (int p = t; p < (PRE_NMS + 31) / 32; p += 1024) rem[p] = 0u;
    __syncthreads();

    int kept = 0;
    for (int i = 0; i < PRE_NMS && kept < POST_NMS; ++i) {
        if (rem[i >> 5] & (1u << (i & 31))) continue;
        if (t == 0) kept_idx[kept] = i;
        float xi1 = bx1[i], yi1 = by1[i], xi2 = bx2[i], yi2 = by2[i], ai = bar[i];
        for (int j = i + 1 + t; j < PRE_NMS; j += 1024) {
            float xx1 = fmaxf(xi1, bx1[j]);
            float yy1 = fmaxf(yi1, by1[j]);
            float xx2 = fminf(xi2, bx2[j]);
            float yy2 = fminf(yi2, by2[j]);
            float iw = fmaxf(0.0f, __fadd_rn(__fsub_rn(xx2, xx1), 1.0f));
            float ih = fmaxf(0.0f, __fadd_rn(__fsub_rn(yy2, yy1), 1.0f));
            float inter = __fmul_rn(iw, ih);
            if (inter > 0.0f) {
                float uni = __fsub_rn(__fadd_rn(ai, bar[j]), inter);
                float iou = __fdiv_rn(inter, uni);
                if (iou > NMS_THRESH_F) atomicOr(&rem[j >> 5], 1u << (j & 31));
            }
        }
        ++kept;
        __syncthreads();
    }

    for (int k = t; k < POST_NMS; k += 1024) {
        size_t o = ((size_t)b * POST_NMS + k) * 5;
        out[o] = (float)b;
        if (k < kept) {
            int ii = kept_idx[k];
            out[o + 1] = bx1[ii]; out[o + 2] = by1[ii];
            out[o + 3] = bx2[ii]; out[o + 4] = by2[ii];
        } else {
            out[o + 1] = 0.0f; out[o + 2] = 0.0f; out[o + 3] = 0.0f; out[o + 4] = 0.0f;
        }
    }
}

extern "C" void kernel_launch(void* const* d_in, const int* in_sizes, int n_in,
                              void* d_out, int out_size, void* d_ws, size_t ws_size,
                              hipStream_t stream)
{
    const float* scores  = (const float*)d_in[0];
    const float* deltas  = (const float*)d_in[1];
    const float* im_info = (const float*)d_in[2];
    const float* anchors = (const float*)d_in[3];
    float* out = (float*)d_out;
    char* ws = (char*)d_ws;

    unsigned* hist             = (unsigned*)(ws + OFF_HIST);
    unsigned* cnt              = (unsigned*)(ws + OFF_CNT);
    unsigned* thresh           = cnt + 8;
    unsigned long long* cand   = (unsigned long long*)(ws + OFF_CAND);
    unsigned* keys             = (unsigned*)(ws + OFF_KEYS);
    float* boxes               = (float*)(ws + OFF_BOXES);
    unsigned* keptbuf          = (unsigned*)(ws + OFF_KEPT);
    unsigned* mask             = (unsigned*)(ws + OFF_MASK);

    hipMemsetAsync(ws, 0, OFF_CAND, stream);

    int total = B_NUM * N_ANCH;
    int blk = 256;
    k_decode_hist<<<(total + blk - 1) / blk, blk, 0, stream>>>(
        scores, deltas, im_info, anchors, hist, keys);
    k_thresh<<<B_NUM, 256, 0, stream>>>(hist, thresh);
    k_compact<<<(total + blk - 1) / blk, blk, 0, stream>>>(keys, thresh, cnt, cand);
    k_sort_gather<<<B_NUM, 1024, 0, stream>>>(cand, cnt, deltas, im_info, anchors, boxes);

    if (ws_size >= (size_t)OFF_MASK + MASK_BYTES) {
        k_iou_mask<<<B_NUM * TRI_TILES, 64, 0, stream>>>(boxes, mask);
        k_nms_scan<<<B_NUM, 64, 0, stream>>>(mask, keptbuf);
        k_nms_gather<<<B_NUM, 320, 0, stream>>>(boxes, keptbuf, out);
    } else {
        k_nms_out<<<B_NUM, 1024, 0, stream>>>(boxes, out);
    }
}

// Round 5
// 441.302 us; speedup vs baseline: 3.2728x; 1.3085x over previous
//
#include <hip/hip_runtime.h>
#include <stdint.h>

#define FEAT_STRIDE_I 16
#define A_NUM 9
#define HH 128
#define WW 128
#define NPIX (HH * WW)            // 16384
#define N_ANCH (NPIX * A_NUM)     // 147456
#define B_NUM 8
#define PRE_NMS 6000
#define POST_NMS 300
#define NMS_THRESH_F 0.7f
#define MIN_SIZE_F 16.0f
#define NEG_INF_F -1e30f
#define NBINS 65536
#define SEGCAP 32768

#define MWORDS 188                 // ceil(6000/32)
#define RT_TILES 94                // ceil(6000/64)
#define TRI_TILES 4465             // RT_TILES*(RT_TILES+1)/2

// ---- workspace layout (bytes) ----
#define OFF_HIST    0u             // 8*65536*4 = 2,097,152  (zeroed)
#define OFF_BINCNT  2097152u       // 8*65536*4 = 2,097,152  (zeroed)
#define OFF_CNT     4194304u       // cnt[8] + thresh[8]     (zeroed, 512B)
#define OFF_BINBASE 4194816u       // 8*65536*4 = 2,097,152
#define OFF_SEG     6291968u       // 8*32768*8 = 2,097,152
#define OFF_KEYS    8389120u       // 8*147456*4 = 4,718,592
#define OFF_BOXES   13107712u      // 8*6000*4*4 = 768,000
#define OFF_KEPT    13875712u      // 8*304*4 = 9,728
#define OFF_MASK    13885440u      // 8*6000*188*4 = 36,096,000 -> end ~49.98 MB
#define MASK_BYTES ((size_t)B_NUM * PRE_NMS * MWORDS * 4)

__device__ __forceinline__ unsigned sortable_f32(float f) {
    unsigned u = __float_as_uint(f);
    return (u & 0x80000000u) ? ~u : (u | 0x80000000u);
}

// Decode one anchor's box exactly in the reference's op order.
__device__ __forceinline__ void decode_box(
    int b, int idx,
    const float* __restrict__ deltas, const float* __restrict__ im_info,
    const float* __restrict__ anchors,
    float& x1, float& y1, float& x2, float& y2, bool& valid)
{
    int a   = idx % A_NUM;
    int pix = idx / A_NUM;
    int w   = pix & (WW - 1);
    int h   = pix >> 7;

    float a0 = anchors[a * 4 + 0];
    float a1 = anchors[a * 4 + 1];
    float a2 = anchors[a * 4 + 2];
    float a3 = anchors[a * 4 + 3];

    float aw = __fadd_rn(__fsub_rn(a2, a0), 1.0f);
    float ah = __fadd_rn(__fsub_rn(a3, a1), 1.0f);
    float sx = (float)(w * FEAT_STRIDE_I);
    float sy = (float)(h * FEAT_STRIDE_I);
    float acx = __fadd_rn(__fadd_rn(sx, a0), __fmul_rn(0.5f, aw));
    float acy = __fadd_rn(__fadd_rn(sy, a1), __fmul_rn(0.5f, ah));

    size_t base = ((size_t)b * 36 + 4 * a) * NPIX + pix;
    float dx = deltas[base];
    float dy = deltas[base + NPIX];
    float dw = deltas[base + 2 * (size_t)NPIX];
    float dh = deltas[base + 3 * (size_t)NPIX];

    float pcx = __fadd_rn(__fmul_rn(dx, aw), acx);
    float pcy = __fadd_rn(__fmul_rn(dy, ah), acy);
    float pw  = __fmul_rn(expf(dw), aw);
    float ph  = __fmul_rn(expf(dh), ah);

    float hx = __fmul_rn(0.5f, pw);
    float hy = __fmul_rn(0.5f, ph);
    x1 = __fsub_rn(pcx, hx);
    y1 = __fsub_rn(pcy, hy);
    x2 = __fadd_rn(pcx, hx);
    y2 = __fadd_rn(pcy, hy);

    float im_h = im_info[b * 3 + 0];
    float im_w = im_info[b * 3 + 1];
    float sc   = im_info[b * 3 + 2];
    float wmax = __fsub_rn(im_w, 1.0f);
    float hmax = __fsub_rn(im_h, 1.0f);

    x1 = fminf(fmaxf(x1, 0.0f), wmax);
    y1 = fminf(fmaxf(y1, 0.0f), hmax);
    x2 = fminf(fmaxf(x2, 0.0f), wmax);
    y2 = fminf(fmaxf(y2, 0.0f), hmax);

    float min_sz = __fmul_rn(MIN_SIZE_F, sc);
    valid = (__fadd_rn(__fsub_rn(x2, x1), 1.0f) >= min_sz) &&
            (__fadd_rn(__fsub_rn(y2, y1), 1.0f) >= min_sz);
}

// K1: decode + masked score -> sortable key; histogram on key>>16.
__global__ void k_decode_hist(
    const float* __restrict__ scores, const float* __restrict__ deltas,
    const float* __restrict__ im_info, const float* __restrict__ anchors,
    unsigned* __restrict__ hist, unsigned* __restrict__ keys)
{
    int gt = blockIdx.x * blockDim.x + threadIdx.x;
    if (gt >= B_NUM * N_ANCH) return;
    int pix  = gt & (NPIX - 1);
    int rest = gt >> 14;
    int a = rest % A_NUM;
    int b = rest / A_NUM;
    int idx = pix * A_NUM + a;

    float x1, y1, x2, y2; bool valid;
    decode_box(b, idx, deltas, im_info, anchors, x1, y1, x2, y2, valid);

    float s = scores[((size_t)b * 18 + 9 + a) * NPIX + pix];
    if (!valid) s = NEG_INF_F;
    unsigned key = sortable_f32(s);
    keys[gt] = key;
    atomicAdd(&hist[b * NBINS + (key >> 16)], 1u);
}

// K2: per batch: suffix-scan histogram (descending bins) -> binbase[bin] =
// #keys in strictly higher bins; find threshold T (highest bin with
// binbase[T]+h[T] >= PRE_NMS); store T and candidate count.
__global__ __launch_bounds__(1024) void k_thresh_scan(
    const unsigned* __restrict__ hist, unsigned* __restrict__ binbase,
    unsigned* __restrict__ cnt, unsigned* __restrict__ thresh)
{
    int b = blockIdx.x;
    int t = threadIdx.x;
    const unsigned* h = hist + (size_t)b * NBINS;
    unsigned* bb = binbase + (size_t)b * NBINS;

    __shared__ unsigned csum[1024];
    __shared__ unsigned sT;
    if (t == 0) sT = 0;

    int base = t * 64;
    unsigned s = 0;
    for (int u = 0; u < 64; ++u) s += h[base + u];
    csum[t] = s;
    __syncthreads();

    // inclusive suffix scan of csum (Hillis-Steele)
    for (int off = 1; off < 1024; off <<= 1) {
        unsigned v = (t + off < 1024) ? csum[t + off] : 0u;
        __syncthreads();
        csum[t] += v;
        __syncthreads();
    }
    unsigned before = csum[t] - s;   // sum over chunks strictly above

    // write binbase for this chunk, walking bins high -> low
    unsigned acc = before;
    for (int bin = base + 63; bin >= base; --bin) {
        bb[bin] = acc;
        acc += h[bin];
    }

    // find highest bin in chunk with cumulative >= PRE_NMS
    unsigned acc2 = before;
    for (int bin = base + 63; bin >= base; --bin) {
        unsigned hh = h[bin];
        if (acc2 + hh >= PRE_NMS) { atomicMax(&sT, (unsigned)bin); break; }
        acc2 += hh;
    }
    __syncthreads();
    if (t == 0) {
        unsigned T = sT;
        thresh[b] = T;
        cnt[b] = bb[T] + h[T];
    }
}

// K3: scatter passing keys (bin >= T) into bin-segmented array.
// Within-bin slot order is nondeterministic; K4's value-based ranking
// restores a deterministic total order (keys are unique via ~idx).
__global__ void k_scatter(
    const unsigned* __restrict__ keys, const unsigned* __restrict__ thresh,
    const unsigned* __restrict__ binbase, unsigned* __restrict__ bincnt,
    unsigned long long* __restrict__ seg)
{
    int gt = blockIdx.x * blockDim.x + threadIdx.x;
    int pix  = gt & (NPIX - 1);
    int rest = gt >> 14;
    int a = rest % A_NUM;
    int b = rest / A_NUM;

    unsigned key = keys[gt];
    unsigned bin = key >> 16;
    if (bin >= thresh[b]) {
        unsigned slot = atomicAdd(&bincnt[(size_t)b * NBINS + bin], 1u);
        unsigned pos = binbase[(size_t)b * NBINS + bin] + slot;
        if (pos < SEGCAP) {
            unsigned idx = (unsigned)(pix * A_NUM + a);
            seg[(size_t)b * SEGCAP + pos] =
                ((unsigned long long)key << 32) | (unsigned long long)(0xFFFFFFFFu - idx);
        }
    }
}

// K4: exact rank within own bin segment + binbase = global rank; decode box
// straight into its sorted slot. 128 blocks x 256 threads per batch.
__global__ __launch_bounds__(256) void k_rank_decode(
    const unsigned long long* __restrict__ seg, const unsigned* __restrict__ cnt,
    const unsigned* __restrict__ binbase, const unsigned* __restrict__ hist,
    const float* __restrict__ deltas, const float* __restrict__ im_info,
    const float* __restrict__ anchors, float* __restrict__ boxes)
{
    int b = blockIdx.x >> 7;
    int p = ((blockIdx.x & 127) << 8) + threadIdx.x;
    unsigned n = cnt[b];
    if (n > SEGCAP) n = SEGCAP;
    if (p >= (int)n) return;

    const unsigned long long* S = seg + (size_t)b * SEGCAP;
    unsigned long long key = S[p];
    unsigned bin = (unsigned)(key >> 48);
    unsigned base = binbase[(size_t)b * NBINS + bin];
    unsigned end = base + hist[(size_t)b * NBINS + bin];
    if (end > SEGCAP) end = SEGCAP;

    unsigned rank = base;
    for (unsigned q = base; q < end; ++q)
        rank += (S[q] > key) ? 1u : 0u;

    if (rank < PRE_NMS) {
        int idx = (int)(0xFFFFFFFFu - (unsigned)(key & 0xFFFFFFFFull));
        float x1, y1, x2, y2; bool v;
        decode_box(b, idx, deltas, im_info, anchors, x1, y1, x2, y2, v);
        float4 o = make_float4(x1, y1, x2, y2);
        *(float4*)(boxes + ((size_t)b * PRE_NMS + rank) * 4) = o;
    }
}

// K5a: upper-triangular IoU suppression bitmask. One wave per (batch, row-tile,
// col-tile) with col-tile >= row-tile. Lower-triangle words are never written;
// garbage there only sets bits for j<i, which are already decided at scan time.
__global__ __launch_bounds__(64) void k_iou_mask(
    const float* __restrict__ boxes, unsigned* __restrict__ mask)
{
    int bid = blockIdx.x;
    int b = bid / TRI_TILES;
    int t = bid - b * TRI_TILES;
    float disc = (float)((2 * RT_TILES + 1) * (2 * RT_TILES + 1) - 8 * t);
    int R = (int)((2.0f * RT_TILES + 1.0f - sqrtf(disc)) * 0.5f);
    while (R > 0 && (R * RT_TILES - (R * (R - 1)) / 2) > t) --R;
    while (((R + 1) * RT_TILES - ((R + 1) * R) / 2) <= t) ++R;
    int C = R + (t - (R * RT_TILES - (R * (R - 1)) / 2));

    int lane = threadIdx.x;
    const float* Bb = boxes + (size_t)b * PRE_NMS * 4;

    int j = C * 64 + lane;
    float jx1 = 0.f, jy1 = 0.f, jx2 = -1.f, jy2 = -1.f, ja = 0.f;
    bool jv = (j < PRE_NMS);
    if (jv) {
        float4 v = *(const float4*)(Bb + 4 * (size_t)j);
        jx1 = v.x; jy1 = v.y; jx2 = v.z; jy2 = v.w;
        ja = __fmul_rn(__fadd_rn(__fsub_rn(jx2, jx1), 1.0f),
                       __fadd_rn(__fsub_rn(jy2, jy1), 1.0f));
    }

    __shared__ float4 rb4[64];
    __shared__ float rba[64];
    int il = R * 64 + lane;
    if (il < PRE_NMS) {
        float4 v = *(const float4*)(Bb + 4 * (size_t)il);
        rb4[lane] = v;
        rba[lane] = __fmul_rn(__fadd_rn(__fsub_rn(v.z, v.x), 1.0f),
                              __fadd_rn(__fsub_rn(v.w, v.y), 1.0f));
    }
    __syncthreads();

    unsigned* Mb = mask + (size_t)b * PRE_NMS * MWORDS;
    int imax = min(64, PRE_NMS - R * 64);
    for (int ri = 0; ri < imax; ++ri) {
        int i = R * 64 + ri;
        float4 bi = rb4[ri];
        float ia = rba[ri];
        float xx1 = fmaxf(bi.x, jx1);
        float yy1 = fmaxf(bi.y, jy1);
        float xx2 = fminf(bi.z, jx2);
        float yy2 = fminf(bi.w, jy2);
        float iw = fmaxf(0.0f, __fadd_rn(__fsub_rn(xx2, xx1), 1.0f));
        float ih = fmaxf(0.0f, __fadd_rn(__fsub_rn(yy2, yy1), 1.0f));
        float inter = __fmul_rn(iw, ih);
        float uni = __fsub_rn(__fadd_rn(ia, ja), inter);
        float iou = __fdiv_rn(inter, uni);
        bool pass = jv && (j > i) && (inter > 0.0f) && (iou > NMS_THRESH_F);
        unsigned long long m = __ballot(pass);
        if (lane == 0)
            *(unsigned long long*)(Mb + (size_t)i * MWORDS + 2 * C) = m;
    }
}

// K5b: serial greedy scan over the bitmask, one wave per batch. Rows are
// prefetched unconditionally 8 deep (static register slots).
__global__ __launch_bounds__(64) void k_nms_scan(
    const unsigned* __restrict__ mask, unsigned* __restrict__ keptbuf)
{
    const int b = blockIdx.x;
    const int l = threadIdx.x;
    __shared__ unsigned supp[MWORDS];
    __shared__ int klist[POST_NMS];
    supp[l] = 0u;
    supp[l + 64] = 0u;
    if (l < MWORDS - 128) supp[l + 128] = 0u;
    __syncthreads();

    const unsigned* __restrict__ M = mask + (size_t)b * PRE_NMS * MWORDS;
    int kept = 0;
    unsigned curw = 0; int curwi = -1;

#define LOADROW(p0, p1, p2, i) { \
        const unsigned* _r = M + (size_t)(((i) < PRE_NMS) ? (i) : (PRE_NMS - 1)) * MWORDS; \
        p0 = _r[l]; p1 = _r[l + 64]; p2 = (l < MWORDS - 128) ? _r[l + 128] : 0u; }

#define STEP(i, p0, p1, p2) { \
        if (kept < POST_NMS) { \
            int _wi = (i) >> 5; \
            if (_wi != curwi) { curw = supp[_wi]; curwi = _wi; } \
            if (!((curw >> ((i) & 31)) & 1u)) { \
                if (l == 0) klist[kept] = (i); \
                supp[l]      |= p0; \
                supp[l + 64] |= p1; \
                if (l < MWORDS - 128) supp[l + 128] |= p2; \
                ++kept; curwi = -1; \
            } \
        } }

    unsigned a0, a1, a2, c0, c1, c2, d0, d1, d2, e0, e1, e2;
    unsigned f0, f1, f2, g0, g1, g2, h0, h1, h2, q0, q1, q2;
    LOADROW(a0, a1, a2, 0) LOADROW(c0, c1, c2, 1)
    LOADROW(d0, d1, d2, 2) LOADROW(e0, e1, e2, 3)
    LOADROW(f0, f1, f2, 4) LOADROW(g0, g1, g2, 5)
    LOADROW(h0, h1, h2, 6) LOADROW(q0, q1, q2, 7)

    for (int i = 0; i < PRE_NMS && kept < POST_NMS; i += 8) {
        STEP(i + 0, a0, a1, a2) LOADROW(a0, a1, a2, i + 8)
        STEP(i + 1, c0, c1, c2) LOADROW(c0, c1, c2, i + 9)
        STEP(i + 2, d0, d1, d2) LOADROW(d0, d1, d2, i + 10)
        STEP(i + 3, e0, e1, e2) LOADROW(e0, e1, e2, i + 11)
        STEP(i + 4, f0, f1, f2) LOADROW(f0, f1, f2, i + 12)
        STEP(i + 5, g0, g1, g2) LOADROW(g0, g1, g2, i + 13)
        STEP(i + 6, h0, h1, h2) LOADROW(h0, h1, h2, i + 14)
        STEP(i + 7, q0, q1, q2) LOADROW(q0, q1, q2, i + 15)
    }
    __syncthreads();
    if (l == 0) keptbuf[b * 304] = (unsigned)kept;
    for (int k = l; k < POST_NMS; k += 64)
        keptbuf[b * 304 + 1 + k] = (k < (int)kept) ? (unsigned)klist[k] : 0u;
#undef LOADROW
#undef STEP
}

// K5c: write output from kept list.
__global__ void k_nms_gather(const float* __restrict__ boxes,
                             const unsigned* __restrict__ keptbuf,
                             float* __restrict__ out)
{
    int b = blockIdx.x;
    int t = threadIdx.x;
    unsigned kept = keptbuf[b * 304];
    if (t < POST_NMS) {
        size_t o = ((size_t)b * POST_NMS + t) * 5;
        float x1 = 0.f, y1 = 0.f, x2 = 0.f, y2 = 0.f;
        if (t < (int)kept) {
            unsigned idx = keptbuf[b * 304 + 1 + t];
            const float4 v = *(const float4*)(boxes + ((size_t)b * PRE_NMS + idx) * 4);
            x1 = v.x; y1 = v.y; x2 = v.z; y2 = v.w;
        }
        out[o + 0] = (float)b;
        out[o + 1] = x1; out[o + 2] = y1; out[o + 3] = x2; out[o + 4] = y2;
    }
}

// Fallback NMS (used only if ws_size is too small for the bitmask).
__global__ __launch_bounds__(1024) void k_nms_out(
    const float* __restrict__ boxes, float* __restrict__ out)
{
    __shared__ float bx1[PRE_NMS], by1[PRE_NMS], bx2[PRE_NMS], by2[PRE_NMS], bar[PRE_NMS];
    __shared__ unsigned rem[(PRE_NMS + 31) / 32];
    __shared__ int kept_idx[POST_NMS];

    int b = blockIdx.x;
    int t = threadIdx.x;

    for (int p = t; p < PRE_NMS; p += 1024) {
        size_t o = ((size_t)b * PRE_NMS + p) * 4;
        float x1 = boxes[o], y1 = boxes[o + 1], x2 = boxes[o + 2], y2 = boxes[o + 3];
        bx1[p] = x1; by1[p] = y1; bx2[p] = x2; by2[p] = y2;
        bar[p] = __fmul_rn(__fadd_rn(__fsub_rn(x2, x1), 1.0f),
                           __fadd_rn(__fsub_rn(y2, y1), 1.0f));
    }
    for (int p = t; p < (PRE_NMS + 31) / 32; p += 1024) rem[p] = 0u;
    __syncthreads();

    int kept = 0;
    for (int i = 0; i < PRE_NMS && kept < POST_NMS; ++i) {
        if (rem[i >> 5] & (1u << (i & 31))) continue;
        if (t == 0) kept_idx[kept] = i;
        float xi1 = bx1[i], yi1 = by1[i], xi2 = bx2[i], yi2 = by2[i], ai = bar[i];
        for (int j = i + 1 + t; j < PRE_NMS; j += 1024) {
            float xx1 = fmaxf(xi1, bx1[j]);
            float yy1 = fmaxf(yi1, by1[j]);
            float xx2 = fminf(xi2, bx2[j]);
            float yy2 = fminf(yi2, by2[j]);
            float iw = fmaxf(0.0f, __fadd_rn(__fsub_rn(xx2, xx1), 1.0f));
            float ih = fmaxf(0.0f, __fadd_rn(__fsub_rn(yy2, yy1), 1.0f));
            float inter = __fmul_rn(iw, ih);
            if (inter > 0.0f) {
                float uni = __fsub_rn(__fadd_rn(ai, bar[j]), inter);
                float iou = __fdiv_rn(inter, uni);
                if (iou > NMS_THRESH_F) atomicOr(&rem[j >> 5], 1u << (j & 31));
            }
        }
        ++kept;
        __syncthreads();
    }

    for (int k = t; k < POST_NMS; k += 1024) {
        size_t o = ((size_t)b * POST_NMS + k) * 5;
        out[o] = (float)b;
        if (k < kept) {
            int ii = kept_idx[k];
            out[o + 1] = bx1[ii]; out[o + 2] = by1[ii];
            out[o + 3] = bx2[ii]; out[o + 4] = by2[ii];
        } else {
            out[o + 1] = 0.0f; out[o + 2] = 0.0f; out[o + 3] = 0.0f; out[o + 4] = 0.0f;
        }
    }
}

extern "C" void kernel_launch(void* const* d_in, const int* in_sizes, int n_in,
                              void* d_out, int out_size, void* d_ws, size_t ws_size,
                              hipStream_t stream)
{
    const float* scores  = (const float*)d_in[0];
    const float* deltas  = (const float*)d_in[1];
    const float* im_info = (const float*)d_in[2];
    const float* anchors = (const float*)d_in[3];
    float* out = (float*)d_out;
    char* ws = (char*)d_ws;

    unsigned* hist             = (unsigned*)(ws + OFF_HIST);
    unsigned* bincnt           = (unsigned*)(ws + OFF_BINCNT);
    unsigned* cnt              = (unsigned*)(ws + OFF_CNT);
    unsigned* thresh           = cnt + 8;
    unsigned* binbase          = (unsigned*)(ws + OFF_BINBASE);
    unsigned long long* seg    = (unsigned long long*)(ws + OFF_SEG);
    unsigned* keys             = (unsigned*)(ws + OFF_KEYS);
    float* boxes               = (float*)(ws + OFF_BOXES);
    unsigned* keptbuf          = (unsigned*)(ws + OFF_KEPT);
    unsigned* mask             = (unsigned*)(ws + OFF_MASK);

    // zero hist + bincnt + cnt/thresh
    hipMemsetAsync(ws, 0, OFF_BINBASE, stream);

    int total = B_NUM * N_ANCH;
    int blk = 256;
    k_decode_hist<<<(total + blk - 1) / blk, blk, 0, stream>>>(
        scores, deltas, im_info, anchors, hist, keys);
    k_thresh_scan<<<B_NUM, 1024, 0, stream>>>(hist, binbase, cnt, thresh);
    k_scatter<<<(total + blk - 1) / blk, blk, 0, stream>>>(
        keys, thresh, binbase, bincnt, seg);
    k_rank_decode<<<B_NUM * 128, 256, 0, stream>>>(
        seg, cnt, binbase, hist, deltas, im_info, anchors, boxes);

    if (ws_size >= (size_t)OFF_MASK + MASK_BYTES) {
        k_iou_mask<<<B_NUM * TRI_TILES, 64, 0, stream>>>(boxes, mask);
        k_nms_scan<<<B_NUM, 64, 0, stream>>>(mask, keptbuf);
        k_nms_gather<<<B_NUM, 320, 0, stream>>>(boxes, keptbuf, out);
    } else {
        k_nms_out<<<B_NUM, 1024, 0, stream>>>(boxes, out);
    }
}

// Round 6
// 343.386 us; speedup vs baseline: 4.2060x; 1.2851x over previous
//
#include <hip/hip_runtime.h>
#include <stdint.h>

#define FEAT_STRIDE_I 16
#define A_NUM 9
#define HH 128
#define WW 128
#define NPIX (HH * WW)            // 16384
#define N_ANCH (NPIX * A_NUM)     // 147456
#define B_NUM 8
#define PRE_NMS 6000
#define POST_NMS 300
#define NMS_THRESH_F 0.7f
#define MIN_SIZE_F 16.0f
#define NEG_INF_F -1e30f
#define NB2 32768                  // 15-bit bins (key>>17)
#define SEGCAP 32768

#define MWORDS 188                 // ceil(6000/32)
#define RT_TILES 94                // ceil(6000/64)
#define TRI_TILES 4465             // RT_TILES*(RT_TILES+1)/2

// swizzled LDS index: chunk walks (stride 32) become conflict-free
#define SW(i) ((i) + ((i) >> 5))

// ---- workspace layout (bytes) ----
#define OFF_BINCNT  0u             // 8*32768*4 = 1,048,576 (zeroed)
#define OFF_CNT     1048576u       // cnt[8] + thresh[8] (512 B)
#define OFF_BINBASE 1049088u       // 8*32768*4 = 1,048,576
#define OFF_HISTG   2097664u       // 8*32768*4 = 1,048,576
#define OFF_SEG     3146240u       // 8*32768*8 = 2,097,152
#define OFF_KEYS    5243392u       // 8*147456*4 = 4,718,592
#define OFF_BOXES   9961984u       // 8*6000*4*4 = 768,000
#define OFF_KEPT    10729984u      // 8*304*4 = 9,728
#define OFF_MASK    10739712u      // 8*6000*188*4 = 36,096,000 -> ~46.8 MB
#define MASK_BYTES ((size_t)B_NUM * PRE_NMS * MWORDS * 4)

__device__ __forceinline__ unsigned sortable_f32(float f) {
    unsigned u = __float_as_uint(f);
    return (u & 0x80000000u) ? ~u : (u | 0x80000000u);
}

// Decode one anchor's box exactly in the reference's op order.
__device__ __forceinline__ void decode_box(
    int b, int idx,
    const float* __restrict__ deltas, const float* __restrict__ im_info,
    const float* __restrict__ anchors,
    float& x1, float& y1, float& x2, float& y2, bool& valid)
{
    int a   = idx % A_NUM;
    int pix = idx / A_NUM;
    int w   = pix & (WW - 1);
    int h   = pix >> 7;

    float a0 = anchors[a * 4 + 0];
    float a1 = anchors[a * 4 + 1];
    float a2 = anchors[a * 4 + 2];
    float a3 = anchors[a * 4 + 3];

    float aw = __fadd_rn(__fsub_rn(a2, a0), 1.0f);
    float ah = __fadd_rn(__fsub_rn(a3, a1), 1.0f);
    float sx = (float)(w * FEAT_STRIDE_I);
    float sy = (float)(h * FEAT_STRIDE_I);
    float acx = __fadd_rn(__fadd_rn(sx, a0), __fmul_rn(0.5f, aw));
    float acy = __fadd_rn(__fadd_rn(sy, a1), __fmul_rn(0.5f, ah));

    size_t base = ((size_t)b * 36 + 4 * a) * NPIX + pix;
    float dx = deltas[base];
    float dy = deltas[base + NPIX];
    float dw = deltas[base + 2 * (size_t)NPIX];
    float dh = deltas[base + 3 * (size_t)NPIX];

    float pcx = __fadd_rn(__fmul_rn(dx, aw), acx);
    float pcy = __fadd_rn(__fmul_rn(dy, ah), acy);
    float pw  = __fmul_rn(expf(dw), aw);
    float ph  = __fmul_rn(expf(dh), ah);

    float hx = __fmul_rn(0.5f, pw);
    float hy = __fmul_rn(0.5f, ph);
    x1 = __fsub_rn(pcx, hx);
    y1 = __fsub_rn(pcy, hy);
    x2 = __fadd_rn(pcx, hx);
    y2 = __fadd_rn(pcy, hy);

    float im_h = im_info[b * 3 + 0];
    float im_w = im_info[b * 3 + 1];
    float sc   = im_info[b * 3 + 2];
    float wmax = __fsub_rn(im_w, 1.0f);
    float hmax = __fsub_rn(im_h, 1.0f);

    x1 = fminf(fmaxf(x1, 0.0f), wmax);
    y1 = fminf(fmaxf(y1, 0.0f), hmax);
    x2 = fminf(fmaxf(x2, 0.0f), wmax);
    y2 = fminf(fmaxf(y2, 0.0f), hmax);

    float min_sz = __fmul_rn(MIN_SIZE_F, sc);
    valid = (__fadd_rn(__fsub_rn(x2, x1), 1.0f) >= min_sz) &&
            (__fadd_rn(__fsub_rn(y2, y1), 1.0f) >= min_sz);
}

// K1: decode + masked score -> sortable key. Pure streaming, no atomics.
__global__ void k_decode(
    const float* __restrict__ scores, const float* __restrict__ deltas,
    const float* __restrict__ im_info, const float* __restrict__ anchors,
    unsigned* __restrict__ keys)
{
    int gt = blockIdx.x * blockDim.x + threadIdx.x;
    if (gt >= B_NUM * N_ANCH) return;
    int pix  = gt & (NPIX - 1);
    int rest = gt >> 14;
    int a = rest % A_NUM;
    int b = rest / A_NUM;
    int idx = pix * A_NUM + a;

    float x1, y1, x2, y2; bool valid;
    decode_box(b, idx, deltas, im_info, anchors, x1, y1, x2, y2, valid);

    float s = scores[((size_t)b * 18 + 9 + a) * NPIX + pix];
    if (!valid) s = NEG_INF_F;
    keys[gt] = sortable_f32(s);
}

// K2: one block per batch. Full 32768-bin histogram in LDS (no global
// atomics), suffix-scan in place, write hist/binbase/thresh/cnt.
__global__ __launch_bounds__(1024) void k_hist_scan(
    const unsigned* __restrict__ keys, unsigned* __restrict__ histg,
    unsigned* __restrict__ binbase, unsigned* __restrict__ cnt,
    unsigned* __restrict__ thresh)
{
    __shared__ unsigned lds[SW(NB2 - 1) + 2];   // 33792 words, swizzled
    __shared__ unsigned csum[1024];
    __shared__ unsigned sT;

    int b = blockIdx.x;
    int t = threadIdx.x;
    if (t == 0) sT = 0;
    for (int i = t; i < SW(NB2 - 1) + 2; i += 1024) lds[i] = 0u;
    __syncthreads();

    // build histogram via LDS atomics
    const unsigned* kb = keys + (size_t)b * N_ANCH;
    for (int i = t; i < N_ANCH; i += 1024)
        atomicAdd(&lds[SW(kb[i] >> 17)], 1u);
    __syncthreads();

    // write hist to global (coalesced)
    unsigned* hg = histg + (size_t)b * NB2;
    for (int i = t; i < NB2; i += 1024) hg[i] = lds[SW(i)];

    // per-thread chunk sum (32 bins, swizzle -> conflict-free)
    int base = t * 32;
    unsigned s = 0;
    for (int u = 0; u < 32; ++u) s += lds[SW(base + u)];
    csum[t] = s;
    __syncthreads();

    // inclusive suffix scan (Hillis-Steele)
    for (int off = 1; off < 1024; off <<= 1) {
        unsigned v = (t + off < 1024) ? csum[t + off] : 0u;
        __syncthreads();
        csum[t] += v;
        __syncthreads();
    }
    unsigned before = csum[t] - s;   // keys in strictly higher chunks

    // find threshold candidate within chunk
    unsigned acc = before;
    for (int bin = base + 31; bin >= base; --bin) {
        unsigned hh = lds[SW(bin)];
        if (acc + hh >= PRE_NMS) { atomicMax(&sT, (unsigned)bin); break; }
        acc += hh;
    }
    __syncthreads();
    unsigned T = sT;

    // walk chunk high->low: overwrite LDS hist with binbase; catch cnt at T
    acc = before;
    for (int bin = base + 31; bin >= base; --bin) {
        unsigned hh = lds[SW(bin)];
        if ((unsigned)bin == T) cnt[b] = acc + hh;
        lds[SW(bin)] = acc;
        acc += hh;
    }
    if (t == 0) thresh[b] = T;
    __syncthreads();

    // write binbase (coalesced)
    unsigned* bb = binbase + (size_t)b * NB2;
    for (int i = t; i < NB2; i += 1024) bb[i] = lds[SW(i)];
}

// K3: scatter passing keys (bin >= T) into bin-segmented array.
__global__ void k_scatter(
    const unsigned* __restrict__ keys, const unsigned* __restrict__ thresh,
    const unsigned* __restrict__ binbase, unsigned* __restrict__ bincnt,
    unsigned long long* __restrict__ seg)
{
    int gt = blockIdx.x * blockDim.x + threadIdx.x;
    int pix  = gt & (NPIX - 1);
    int rest = gt >> 14;
    int a = rest % A_NUM;
    int b = rest / A_NUM;

    unsigned key = keys[gt];
    unsigned bin = key >> 17;
    if (bin >= thresh[b]) {
        unsigned slot = atomicAdd(&bincnt[(size_t)b * NB2 + bin], 1u);
        unsigned pos = binbase[(size_t)b * NB2 + bin] + slot;
        if (pos < SEGCAP) {
            unsigned idx = (unsigned)(pix * A_NUM + a);
            seg[(size_t)b * SEGCAP + pos] =
                ((unsigned long long)key << 32) | (unsigned long long)(0xFFFFFFFFu - idx);
        }
    }
}

// K4: exact rank within own bin segment + binbase = global rank; decode box
// straight into its sorted slot.
__global__ __launch_bounds__(256) void k_rank_decode(
    const unsigned long long* __restrict__ seg, const unsigned* __restrict__ cnt,
    const unsigned* __restrict__ binbase, const unsigned* __restrict__ histg,
    const float* __restrict__ deltas, const float* __restrict__ im_info,
    const float* __restrict__ anchors, float* __restrict__ boxes)
{
    int b = blockIdx.x >> 7;
    int p = ((blockIdx.x & 127) << 8) + threadIdx.x;
    unsigned n = cnt[b];
    if (n > SEGCAP) n = SEGCAP;
    if (p >= (int)n) return;

    const unsigned long long* S = seg + (size_t)b * SEGCAP;
    unsigned long long key = S[p];
    unsigned bin = (unsigned)(key >> 49);
    unsigned base = binbase[(size_t)b * NB2 + bin];
    unsigned end = base + histg[(size_t)b * NB2 + bin];
    if (end > SEGCAP) end = SEGCAP;

    unsigned rank = base;
    for (unsigned q = base; q < end; ++q)
        rank += (S[q] > key) ? 1u : 0u;

    if (rank < PRE_NMS) {
        int idx = (int)(0xFFFFFFFFu - (unsigned)(key & 0xFFFFFFFFull));
        float x1, y1, x2, y2; bool v;
        decode_box(b, idx, deltas, im_info, anchors, x1, y1, x2, y2, v);
        float4 o = make_float4(x1, y1, x2, y2);
        *(float4*)(boxes + ((size_t)b * PRE_NMS + rank) * 4) = o;
    }
}

// K5a: upper-triangular IoU suppression bitmask.
__global__ __launch_bounds__(64) void k_iou_mask(
    const float* __restrict__ boxes, unsigned* __restrict__ mask)
{
    int bid = blockIdx.x;
    int b = bid / TRI_TILES;
    int t = bid - b * TRI_TILES;
    float disc = (float)((2 * RT_TILES + 1) * (2 * RT_TILES + 1) - 8 * t);
    int R = (int)((2.0f * RT_TILES + 1.0f - sqrtf(disc)) * 0.5f);
    while (R > 0 && (R * RT_TILES - (R * (R - 1)) / 2) > t) --R;
    while (((R + 1) * RT_TILES - ((R + 1) * R) / 2) <= t) ++R;
    int C = R + (t - (R * RT_TILES - (R * (R - 1)) / 2));

    int lane = threadIdx.x;
    const float* Bb = boxes + (size_t)b * PRE_NMS * 4;

    int j = C * 64 + lane;
    float jx1 = 0.f, jy1 = 0.f, jx2 = -1.f, jy2 = -1.f, ja = 0.f;
    bool jv = (j < PRE_NMS);
    if (jv) {
        float4 v = *(const float4*)(Bb + 4 * (size_t)j);
        jx1 = v.x; jy1 = v.y; jx2 = v.z; jy2 = v.w;
        ja = __fmul_rn(__fadd_rn(__fsub_rn(jx2, jx1), 1.0f),
                       __fadd_rn(__fsub_rn(jy2, jy1), 1.0f));
    }

    __shared__ float4 rb4[64];
    __shared__ float rba[64];
    int il = R * 64 + lane;
    if (il < PRE_NMS) {
        float4 v = *(const float4*)(Bb + 4 * (size_t)il);
        rb4[lane] = v;
        rba[lane] = __fmul_rn(__fadd_rn(__fsub_rn(v.z, v.x), 1.0f),
                              __fadd_rn(__fsub_rn(v.w, v.y), 1.0f));
    }
    __syncthreads();

    unsigned* Mb = mask + (size_t)b * PRE_NMS * MWORDS;
    int imax = min(64, PRE_NMS - R * 64);
    for (int ri = 0; ri < imax; ++ri) {
        int i = R * 64 + ri;
        float4 bi = rb4[ri];
        float ia = rba[ri];
        float xx1 = fmaxf(bi.x, jx1);
        float yy1 = fmaxf(bi.y, jy1);
        float xx2 = fminf(bi.z, jx2);
        float yy2 = fminf(bi.w, jy2);
        float iw = fmaxf(0.0f, __fadd_rn(__fsub_rn(xx2, xx1), 1.0f));
        float ih = fmaxf(0.0f, __fadd_rn(__fsub_rn(yy2, yy1), 1.0f));
        float inter = __fmul_rn(iw, ih);
        float uni = __fsub_rn(__fadd_rn(ia, ja), inter);
        float iou = __fdiv_rn(inter, uni);
        bool pass = jv && (j > i) && (inter > 0.0f) && (iou > NMS_THRESH_F);
        unsigned long long m = __ballot(pass);
        if (lane == 0)
            *(unsigned long long*)(Mb + (size_t)i * MWORDS + 2 * C) = m;
    }
}

// K5b: serial greedy scan over the bitmask, one wave per batch, 8-deep
// unconditional row prefetch (static register slots).
__global__ __launch_bounds__(64) void k_nms_scan(
    const unsigned* __restrict__ mask, unsigned* __restrict__ keptbuf)
{
    const int b = blockIdx.x;
    const int l = threadIdx.x;
    __shared__ unsigned supp[MWORDS];
    __shared__ int klist[POST_NMS];
    supp[l] = 0u;
    supp[l + 64] = 0u;
    if (l < MWORDS - 128) supp[l + 128] = 0u;
    __syncthreads();

    const unsigned* __restrict__ M = mask + (size_t)b * PRE_NMS * MWORDS;
    int kept = 0;
    unsigned curw = 0; int curwi = -1;

#define LOADROW(p0, p1, p2, i) { \
        const unsigned* _r = M + (size_t)(((i) < PRE_NMS) ? (i) : (PRE_NMS - 1)) * MWORDS; \
        p0 = _r[l]; p1 = _r[l + 64]; p2 = (l < MWORDS - 128) ? _r[l + 128] : 0u; }

#define STEP(i, p0, p1, p2) { \
        if (kept < POST_NMS) { \
            int _wi = (i) >> 5; \
            if (_wi != curwi) { curw = supp[_wi]; curwi = _wi; } \
            if (!((curw >> ((i) & 31)) & 1u)) { \
                if (l == 0) klist[kept] = (i); \
                supp[l]      |= p0; \
                supp[l + 64] |= p1; \
                if (l < MWORDS - 128) supp[l + 128] |= p2; \
                ++kept; curwi = -1; \
            } \
        } }

    unsigned a0, a1, a2, c0, c1, c2, d0, d1, d2, e0, e1, e2;
    unsigned f0, f1, f2, g0, g1, g2, h0, h1, h2, q0, q1, q2;
    LOADROW(a0, a1, a2, 0) LOADROW(c0, c1, c2, 1)
    LOADROW(d0, d1, d2, 2) LOADROW(e0, e1, e2, 3)
    LOADROW(f0, f1, f2, 4) LOADROW(g0, g1, g2, 5)
    LOADROW(h0, h1, h2, 6) LOADROW(q0, q1, q2, 7)

    for (int i = 0; i < PRE_NMS && kept < POST_NMS; i += 8) {
        STEP(i + 0, a0, a1, a2) LOADROW(a0, a1, a2, i + 8)
        STEP(i + 1, c0, c1, c2) LOADROW(c0, c1, c2, i + 9)
        STEP(i + 2, d0, d1, d2) LOADROW(d0, d1, d2, i + 10)
        STEP(i + 3, e0, e1, e2) LOADROW(e0, e1, e2, i + 11)
        STEP(i + 4, f0, f1, f2) LOADROW(f0, f1, f2, i + 12)
        STEP(i + 5, g0, g1, g2) LOADROW(g0, g1, g2, i + 13)
        STEP(i + 6, h0, h1, h2) LOADROW(h0, h1, h2, i + 14)
        STEP(i + 7, q0, q1, q2) LOADROW(q0, q1, q2, i + 15)
    }
    __syncthreads();
    if (l == 0) keptbuf[b * 304] = (unsigned)kept;
    for (int k = l; k < POST_NMS; k += 64)
        keptbuf[b * 304 + 1 + k] = (k < (int)kept) ? (unsigned)klist[k] : 0u;
#undef LOADROW
#undef STEP
}

// K5c: write output from kept list.
__global__ void k_nms_gather(const float* __restrict__ boxes,
                             const unsigned* __restrict__ keptbuf,
                             float* __restrict__ out)
{
    int b = blockIdx.x;
    int t = threadIdx.x;
    unsigned kept = keptbuf[b * 304];
    if (t < POST_NMS) {
        size_t o = ((size_t)b * POST_NMS + t) * 5;
        float x1 = 0.f, y1 = 0.f, x2 = 0.f, y2 = 0.f;
        if (t < (int)kept) {
            unsigned idx = keptbuf[b * 304 + 1 + t];
            const float4 v = *(const float4*)(boxes + ((size_t)b * PRE_NMS + idx) * 4);
            x1 = v.x; y1 = v.y; x2 = v.z; y2 = v.w;
        }
        out[o + 0] = (float)b;
        out[o + 1] = x1; out[o + 2] = y1; out[o + 3] = x2; out[o + 4] = y2;
    }
}

// Fallback NMS (used only if ws_size is too small for the bitmask).
__global__ __launch_bounds__(1024) void k_nms_out(
    const float* __restrict__ boxes, float* __restrict__ out)
{
    __shared__ float bx1[PRE_NMS], by1[PRE_NMS], bx2[PRE_NMS], by2[PRE_NMS], bar[PRE_NMS];
    __shared__ unsigned rem[(PRE_NMS + 31) / 32];
    __shared__ int kept_idx[POST_NMS];

    int b = blockIdx.x;
    int t = threadIdx.x;

    for (int p = t; p < PRE_NMS; p += 1024) {
        size_t o = ((size_t)b * PRE_NMS + p) * 4;
        float x1 = boxes[o], y1 = boxes[o + 1], x2 = boxes[o + 2], y2 = boxes[o + 3];
        bx1[p] = x1; by1[p] = y1; bx2[p] = x2; by2[p] = y2;
        bar[p] = __fmul_rn(__fadd_rn(__fsub_rn(x2, x1), 1.0f),
                           __fadd_rn(__fsub_rn(y2, y1), 1.0f));
    }
    for (int p = t; p < (PRE_NMS + 31) / 32; p += 1024) rem[p] = 0u;
    __syncthreads();

    int kept = 0;
    for (int i = 0; i < PRE_NMS && kept < POST_NMS; ++i) {
        if (rem[i >> 5] & (1u << (i & 31))) continue;
        if (t == 0) kept_idx[kept] = i;
        float xi1 = bx1[i], yi1 = by1[i], xi2 = bx2[i], yi2 = by2[i], ai = bar[i];
        for (int j = i + 1 + t; j < PRE_NMS; j += 1024) {
            float xx1 = fmaxf(xi1, bx1[j]);
            float yy1 = fmaxf(yi1, by1[j]);
            float xx2 = fminf(xi2, bx2[j]);
            float yy2 = fminf(yi2, by2[j]);
            float iw = fmaxf(0.0f, __fadd_rn(__fsub_rn(xx2, xx1), 1.0f));
            float ih = fmaxf(0.0f, __fadd_rn(__fsub_rn(yy2, yy1), 1.0f));
            float inter = __fmul_rn(iw, ih);
            if (inter > 0.0f) {
                float uni = __fsub_rn(__fadd_rn(ai, bar[j]), inter);
                float iou = __fdiv_rn(inter, uni);
                if (iou > NMS_THRESH_F) atomicOr(&rem[j >> 5], 1u << (j & 31));
            }
        }
        ++kept;
        __syncthreads();
    }

    for (int k = t; k < POST_NMS; k += 1024) {
        size_t o = ((size_t)b * POST_NMS + k) * 5;
        out[o] = (float)b;
        if (k < kept) {
            int ii = kept_idx[k];
            out[o + 1] = bx1[ii]; out[o + 2] = by1[ii];
            out[o + 3] = bx2[ii]; out[o + 4] = by2[ii];
        } else {
            out[o + 1] = 0.0f; out[o + 2] = 0.0f; out[o + 3] = 0.0f; out[o + 4] = 0.0f;
        }
    }
}

extern "C" void kernel_launch(void* const* d_in, const int* in_sizes, int n_in,
                              void* d_out, int out_size, void* d_ws, size_t ws_size,
                              hipStream_t stream)
{
    const float* scores  = (const float*)d_in[0];
    const float* deltas  = (const float*)d_in[1];
    const float* im_info = (const float*)d_in[2];
    const float* anchors = (const float*)d_in[3];
    float* out = (float*)d_out;
    char* ws = (char*)d_ws;

    unsigned* bincnt           = (unsigned*)(ws + OFF_BINCNT);
    unsigned* cnt              = (unsigned*)(ws + OFF_CNT);
    unsigned* thresh           = cnt + 8;
    unsigned* binbase          = (unsigned*)(ws + OFF_BINBASE);
    unsigned* histg            = (unsigned*)(ws + OFF_HISTG);
    unsigned long long* seg    = (unsigned long long*)(ws + OFF_SEG);
    unsigned* keys             = (unsigned*)(ws + OFF_KEYS);
    float* boxes               = (float*)(ws + OFF_BOXES);
    unsigned* keptbuf          = (unsigned*)(ws + OFF_KEPT);
    unsigned* mask             = (unsigned*)(ws + OFF_MASK);

    // zero bin counters only
    hipMemsetAsync(ws, 0, OFF_CNT, stream);

    int total = B_NUM * N_ANCH;
    int blk = 256;
    k_decode<<<(total + blk - 1) / blk, blk, 0, stream>>>(
        scores, deltas, im_info, anchors, keys);
    k_hist_scan<<<B_NUM, 1024, 0, stream>>>(keys, histg, binbase, cnt, thresh);
    k_scatter<<<(total + blk - 1) / blk, blk, 0, stream>>>(
        keys, thresh, binbase, bincnt, seg);
    k_rank_decode<<<B_NUM * 128, 256, 0, stream>>>(
        seg, cnt, binbase, histg, deltas, im_info, anchors, boxes);

    if (ws_size >= (size_t)OFF_MASK + MASK_BYTES) {
        k_iou_mask<<<B_NUM * TRI_TILES, 64, 0, stream>>>(boxes, mask);
        k_nms_scan<<<B_NUM, 64, 0, stream>>>(mask, keptbuf);
        k_nms_gather<<<B_NUM, 320, 0, stream>>>(boxes, keptbuf, out);
    } else {
        k_nms_out<<<B_NUM, 1024, 0, stream>>>(boxes, out);
    }
}

// Round 7
// 324.389 us; speedup vs baseline: 4.4523x; 1.0586x over previous
//
#include <hip/hip_runtime.h>
#include <stdint.h>

#define FEAT_STRIDE_I 16
#define A_NUM 9
#define HH 128
#define WW 128
#define NPIX (HH * WW)            // 16384
#define N_ANCH (NPIX * A_NUM)     // 147456
#define B_NUM 8
#define PRE_NMS 6000
#define POST_NMS 300
#define NMS_THRESH_F 0.7f
#define MIN_SIZE_F 16.0f
#define NEG_INF_F -1e30f
#define NB2 32768                  // 15-bit bins (key>>17)
#define SEGCAP 16384

#define RT_TILES 94                // ceil(6000/64)
#define TRI_TILES 4465             // RT_TILES*(RT_TILES+1)/2
#define BQWORDS (RT_TILES * RT_TILES * 64)   // 565,504 qwords per batch

// swizzled LDS index: chunk walks (stride 32) become conflict-free
#define SW(i) ((i) + ((i) >> 5))

// ---- workspace layout (bytes) ----
#define OFF_BINCNT  0u             // 8*32768*4 = 1,048,576 (zeroed)
#define OFF_CNT     1048576u       // cnt[8] + thresh[8] (512 B)
#define OFF_BINBASE 1049088u       // 1,048,576
#define OFF_HISTG   2097664u       // 1,048,576
#define OFF_SEG     3146240u       // 8*16384*8 = 1,048,576
#define OFF_KEYS    4194816u       // 8*147456*4 = 4,718,592
#define OFF_BOXES   8913408u       // 8*6000*4*4 = 768,000
#define OFF_KEPT    9681408u       // 8*304*4 = 9,728
#define OFF_MASK    9691136u       // 8*565504*8 = 36,192,256 -> end 45,883,392
#define MASK_BYTES ((size_t)B_NUM * BQWORDS * 8)

__device__ __forceinline__ unsigned sortable_f32(float f) {
    unsigned u = __float_as_uint(f);
    return (u & 0x80000000u) ? ~u : (u | 0x80000000u);
}

// Decode one anchor's box exactly in the reference's op order.
__device__ __forceinline__ void decode_box(
    int b, int idx,
    const float* __restrict__ deltas, const float* __restrict__ im_info,
    const float* __restrict__ anchors,
    float& x1, float& y1, float& x2, float& y2, bool& valid)
{
    int a   = idx % A_NUM;
    int pix = idx / A_NUM;
    int w   = pix & (WW - 1);
    int h   = pix >> 7;

    float a0 = anchors[a * 4 + 0];
    float a1 = anchors[a * 4 + 1];
    float a2 = anchors[a * 4 + 2];
    float a3 = anchors[a * 4 + 3];

    float aw = __fadd_rn(__fsub_rn(a2, a0), 1.0f);
    float ah = __fadd_rn(__fsub_rn(a3, a1), 1.0f);
    float sx = (float)(w * FEAT_STRIDE_I);
    float sy = (float)(h * FEAT_STRIDE_I);
    float acx = __fadd_rn(__fadd_rn(sx, a0), __fmul_rn(0.5f, aw));
    float acy = __fadd_rn(__fadd_rn(sy, a1), __fmul_rn(0.5f, ah));

    size_t base = ((size_t)b * 36 + 4 * a) * NPIX + pix;
    float dx = deltas[base];
    float dy = deltas[base + NPIX];
    float dw = deltas[base + 2 * (size_t)NPIX];
    float dh = deltas[base + 3 * (size_t)NPIX];

    float pcx = __fadd_rn(__fmul_rn(dx, aw), acx);
    float pcy = __fadd_rn(__fmul_rn(dy, ah), acy);
    float pw  = __fmul_rn(expf(dw), aw);
    float ph  = __fmul_rn(expf(dh), ah);

    float hx = __fmul_rn(0.5f, pw);
    float hy = __fmul_rn(0.5f, ph);
    x1 = __fsub_rn(pcx, hx);
    y1 = __fsub_rn(pcy, hy);
    x2 = __fadd_rn(pcx, hx);
    y2 = __fadd_rn(pcy, hy);

    float im_h = im_info[b * 3 + 0];
    float im_w = im_info[b * 3 + 1];
    float sc   = im_info[b * 3 + 2];
    float wmax = __fsub_rn(im_w, 1.0f);
    float hmax = __fsub_rn(im_h, 1.0f);

    x1 = fminf(fmaxf(x1, 0.0f), wmax);
    y1 = fminf(fmaxf(y1, 0.0f), hmax);
    x2 = fminf(fmaxf(x2, 0.0f), wmax);
    y2 = fminf(fmaxf(y2, 0.0f), hmax);

    float min_sz = __fmul_rn(MIN_SIZE_F, sc);
    valid = (__fadd_rn(__fsub_rn(x2, x1), 1.0f) >= min_sz) &&
            (__fadd_rn(__fsub_rn(y2, y1), 1.0f) >= min_sz);
}

// K1: decode + masked score -> sortable key. Pure streaming, no atomics.
__global__ void k_decode(
    const float* __restrict__ scores, const float* __restrict__ deltas,
    const float* __restrict__ im_info, const float* __restrict__ anchors,
    unsigned* __restrict__ keys)
{
    int gt = blockIdx.x * blockDim.x + threadIdx.x;
    if (gt >= B_NUM * N_ANCH) return;
    int pix  = gt & (NPIX - 1);
    int rest = gt >> 14;
    int a = rest % A_NUM;
    int b = rest / A_NUM;
    int idx = pix * A_NUM + a;

    float x1, y1, x2, y2; bool valid;
    decode_box(b, idx, deltas, im_info, anchors, x1, y1, x2, y2, valid);

    float s = scores[((size_t)b * 18 + 9 + a) * NPIX + pix];
    if (!valid) s = NEG_INF_F;
    keys[gt] = sortable_f32(s);
}

// K2: one block per batch. Full 32768-bin histogram in LDS (no global
// atomics), suffix-scan in place, write hist/binbase/thresh/cnt.
__global__ __launch_bounds__(1024) void k_hist_scan(
    const unsigned* __restrict__ keys, unsigned* __restrict__ histg,
    unsigned* __restrict__ binbase, unsigned* __restrict__ cnt,
    unsigned* __restrict__ thresh)
{
    __shared__ unsigned lds[SW(NB2 - 1) + 2];   // 33792 words, swizzled
    __shared__ unsigned csum[1024];
    __shared__ unsigned sT;

    int b = blockIdx.x;
    int t = threadIdx.x;
    if (t == 0) sT = 0;
    for (int i = t; i < SW(NB2 - 1) + 2; i += 1024) lds[i] = 0u;
    __syncthreads();

    // build histogram via LDS atomics
    const unsigned* kb = keys + (size_t)b * N_ANCH;
    for (int i = t; i < N_ANCH; i += 1024)
        atomicAdd(&lds[SW(kb[i] >> 17)], 1u);
    __syncthreads();

    // write hist to global (coalesced)
    unsigned* hg = histg + (size_t)b * NB2;
    for (int i = t; i < NB2; i += 1024) hg[i] = lds[SW(i)];

    // per-thread chunk sum (32 bins, swizzle -> conflict-free)
    int base = t * 32;
    unsigned s = 0;
    for (int u = 0; u < 32; ++u) s += lds[SW(base + u)];
    csum[t] = s;
    __syncthreads();

    // inclusive suffix scan (Hillis-Steele)
    for (int off = 1; off < 1024; off <<= 1) {
        unsigned v = (t + off < 1024) ? csum[t + off] : 0u;
        __syncthreads();
        csum[t] += v;
        __syncthreads();
    }
    unsigned before = csum[t] - s;   // keys in strictly higher chunks

    // find threshold candidate within chunk
    unsigned acc = before;
    for (int bin = base + 31; bin >= base; --bin) {
        unsigned hh = lds[SW(bin)];
        if (acc + hh >= PRE_NMS) { atomicMax(&sT, (unsigned)bin); break; }
        acc += hh;
    }
    __syncthreads();
    unsigned T = sT;

    // walk chunk high->low: overwrite LDS hist with binbase; catch cnt at T
    acc = before;
    for (int bin = base + 31; bin >= base; --bin) {
        unsigned hh = lds[SW(bin)];
        if ((unsigned)bin == T) cnt[b] = acc + hh;
        lds[SW(bin)] = acc;
        acc += hh;
    }
    if (t == 0) thresh[b] = T;
    __syncthreads();

    // write binbase (coalesced)
    unsigned* bb = binbase + (size_t)b * NB2;
    for (int i = t; i < NB2; i += 1024) bb[i] = lds[SW(i)];
}

// K3: scatter passing keys (bin >= T) into bin-segmented array.
__global__ void k_scatter(
    const unsigned* __restrict__ keys, const unsigned* __restrict__ thresh,
    const unsigned* __restrict__ binbase, unsigned* __restrict__ bincnt,
    unsigned long long* __restrict__ seg)
{
    int gt = blockIdx.x * blockDim.x + threadIdx.x;
    int pix  = gt & (NPIX - 1);
    int rest = gt >> 14;
    int a = rest % A_NUM;
    int b = rest / A_NUM;

    unsigned key = keys[gt];
    unsigned bin = key >> 17;
    if (bin >= thresh[b]) {
        unsigned slot = atomicAdd(&bincnt[(size_t)b * NB2 + bin], 1u);
        unsigned pos = binbase[(size_t)b * NB2 + bin] + slot;
        if (pos < SEGCAP) {
            unsigned idx = (unsigned)(pix * A_NUM + a);
            seg[(size_t)b * SEGCAP + pos] =
                ((unsigned long long)key << 32) | (unsigned long long)(0xFFFFFFFFu - idx);
        }
    }
}

// K4: exact rank within own bin segment + binbase = global rank; decode box
// straight into its sorted slot.
__global__ __launch_bounds__(256) void k_rank_decode(
    const unsigned long long* __restrict__ seg, const unsigned* __restrict__ cnt,
    const unsigned* __restrict__ binbase, const unsigned* __restrict__ histg,
    const float* __restrict__ deltas, const float* __restrict__ im_info,
    const float* __restrict__ anchors, float* __restrict__ boxes)
{
    int b = blockIdx.x >> 7;
    int p = ((blockIdx.x & 127) << 8) + threadIdx.x;
    unsigned n = cnt[b];
    if (n > SEGCAP) n = SEGCAP;
    if (p >= (int)n) return;

    const unsigned long long* S = seg + (size_t)b * SEGCAP;
    unsigned long long key = S[p];
    unsigned bin = (unsigned)(key >> 49);
    unsigned base = binbase[(size_t)b * NB2 + bin];
    unsigned end = base + histg[(size_t)b * NB2 + bin];
    if (end > SEGCAP) end = SEGCAP;

    unsigned rank = base;
    for (unsigned q = base; q < end; ++q)
        rank += (S[q] > key) ? 1u : 0u;

    if (rank < PRE_NMS) {
        int idx = (int)(0xFFFFFFFFu - (unsigned)(key & 0xFFFFFFFFull));
        float x1, y1, x2, y2; bool v;
        decode_box(b, idx, deltas, im_info, anchors, x1, y1, x2, y2, v);
        float4 o = make_float4(x1, y1, x2, y2);
        *(float4*)(boxes + ((size_t)b * PRE_NMS + rank) * 4) = o;
    }
}

// K5a: upper-triangular IoU suppression bitmask, blocked layout
// mask[b][R][C][64] (u64). Each wave computes a 64x64 bit block; row words
// accumulate in per-lane registers via ballot+select, then one coalesced
// 512B store. Division eliminated except in a +-6e-7*uni boundary band:
//   t = RN(0.7*uni) has |t - 0.7*uni| <= 0.7*uni*2^-24 (~4.2e-8*uni);
//   RN(inter/uni) errs <= 0.5 ulp (~3e-8 rel). |inter - t| > 6e-7*uni
//   implies the exact ratio is >5 ulps away from 0.7, so the compare
//   decision equals the reference's. Borderline lanes do exact __fdiv_rn.
__global__ __launch_bounds__(64) void k_iou_mask(
    const float* __restrict__ boxes, unsigned long long* __restrict__ mask)
{
    int bid = blockIdx.x;
    int b = bid / TRI_TILES;
    int t = bid - b * TRI_TILES;
    float disc = (float)((2 * RT_TILES + 1) * (2 * RT_TILES + 1) - 8 * t);
    int R = (int)((2.0f * RT_TILES + 1.0f - sqrtf(disc)) * 0.5f);
    while (R > 0 && (R * RT_TILES - (R * (R - 1)) / 2) > t) --R;
    while (((R + 1) * RT_TILES - ((R + 1) * R) / 2) <= t) ++R;
    int C = R + (t - (R * RT_TILES - (R * (R - 1)) / 2));

    int lane = threadIdx.x;
    const float* Bb = boxes + (size_t)b * PRE_NMS * 4;

    int j = C * 64 + lane;
    float jx1 = 0.f, jy1 = 0.f, jx2 = -1.f, jy2 = -1.f, ja = 0.f;
    bool jv = (j < PRE_NMS);
    if (jv) {
        float4 v = *(const float4*)(Bb + 4 * (size_t)j);
        jx1 = v.x; jy1 = v.y; jx2 = v.z; jy2 = v.w;
        ja = __fmul_rn(__fadd_rn(__fsub_rn(jx2, jx1), 1.0f),
                       __fadd_rn(__fsub_rn(jy2, jy1), 1.0f));
    }

    __shared__ float4 rb4[64];
    __shared__ float rba[64];
    int il = R * 64 + lane;
    if (il < PRE_NMS) {
        float4 v = *(const float4*)(Bb + 4 * (size_t)il);
        rb4[lane] = v;
        rba[lane] = __fmul_rn(__fadd_rn(__fsub_rn(v.z, v.x), 1.0f),
                              __fadd_rn(__fsub_rn(v.w, v.y), 1.0f));
    }
    __syncthreads();

    unsigned long long myword = 0ULL;
    for (int ri = 0; ri < 64; ++ri) {
        int i = R * 64 + ri;
        float4 bi = rb4[ri];
        float ia = rba[ri];
        float xx1 = fmaxf(bi.x, jx1);
        float yy1 = fmaxf(bi.y, jy1);
        float xx2 = fminf(bi.z, jx2);
        float yy2 = fminf(bi.w, jy2);
        float iw = fmaxf(0.0f, __fadd_rn(__fsub_rn(xx2, xx1), 1.0f));
        float ih = fmaxf(0.0f, __fadd_rn(__fsub_rn(yy2, yy1), 1.0f));
        float inter = __fmul_rn(iw, ih);
        float uni = __fsub_rn(__fadd_rn(ia, ja), inter);
        float tcut = __fmul_rn(NMS_THRESH_F, uni);
        float diff = __fsub_rn(inter, tcut);
        bool sup = diff > 0.0f;
        if (fabsf(diff) <= 6e-7f * uni) {          // rare boundary band
            sup = __fdiv_rn(inter, uni) > NMS_THRESH_F;
        }
        bool pass = jv && (j > i) && (inter > 0.0f) && sup;
        unsigned long long m = __ballot(pass);
        myword = (lane == ri) ? m : myword;
    }
    mask[(size_t)b * BQWORDS + ((size_t)(R * RT_TILES + C) * 64 + lane)] = myword;
}

// K5b: serial greedy scan over the blocked bitmask, one wave per batch.
// Row i's 94 qwords live at M[(R*94+C)*64 + r], C = 0..93 (stride 512B).
// Lane l covers C=l and (l<30) C=64+l. 8-deep unconditional prefetch.
__global__ __launch_bounds__(64) void k_nms_scan(
    const unsigned long long* __restrict__ mask, unsigned* __restrict__ keptbuf)
{
    const int b = blockIdx.x;
    const int l = threadIdx.x;
    __shared__ unsigned long long supp[RT_TILES];
    __shared__ int klist[POST_NMS];
    supp[l] = 0ULL;
    if (l < RT_TILES - 64) supp[l + 64] = 0ULL;
    __syncthreads();

    const unsigned long long* __restrict__ M = mask + (size_t)b * BQWORDS;
    int kept = 0;
    unsigned long long curw = 0; int curwi = -1;

#define LOADROW(p0, p1, i) { \
        int _i = ((i) < PRE_NMS) ? (i) : (PRE_NMS - 1); \
        const unsigned long long* _r = M + (size_t)((_i >> 6) * RT_TILES) * 64 + (_i & 63); \
        p0 = _r[l * 64]; \
        p1 = (l < RT_TILES - 64) ? _r[(64 + l) * 64] : 0ULL; }

#define STEP(i, p0, p1) { \
        if (kept < POST_NMS) { \
            int _wi = (i) >> 6; \
            if (_wi != curwi) { curw = supp[_wi]; curwi = _wi; } \
            if (!((curw >> ((i) & 63)) & 1ULL)) { \
                if (l == 0) klist[kept] = (i); \
                supp[l] |= p0; \
                if (l < RT_TILES - 64) supp[l + 64] |= p1; \
                ++kept; curwi = -1; \
            } \
        } }

    unsigned long long a0, a1, c0, c1, d0, d1, e0, e1;
    unsigned long long f0, f1, g0, g1, h0, h1, q0, q1;
    LOADROW(a0, a1, 0) LOADROW(c0, c1, 1)
    LOADROW(d0, d1, 2) LOADROW(e0, e1, 3)
    LOADROW(f0, f1, 4) LOADROW(g0, g1, 5)
    LOADROW(h0, h1, 6) LOADROW(q0, q1, 7)

    for (int i = 0; i < PRE_NMS && kept < POST_NMS; i += 8) {
        STEP(i + 0, a0, a1) LOADROW(a0, a1, i + 8)
        STEP(i + 1, c0, c1) LOADROW(c0, c1, i + 9)
        STEP(i + 2, d0, d1) LOADROW(d0, d1, i + 10)
        STEP(i + 3, e0, e1) LOADROW(e0, e1, i + 11)
        STEP(i + 4, f0, f1) LOADROW(f0, f1, i + 12)
        STEP(i + 5, g0, g1) LOADROW(g0, g1, i + 13)
        STEP(i + 6, h0, h1) LOADROW(h0, h1, i + 14)
        STEP(i + 7, q0, q1) LOADROW(q0, q1, i + 15)
    }
    __syncthreads();
    if (l == 0) keptbuf[b * 304] = (unsigned)kept;
    for (int k = l; k < POST_NMS; k += 64)
        keptbuf[b * 304 + 1 + k] = (k < (int)kept) ? (unsigned)klist[k] : 0u;
#undef LOADROW
#undef STEP
}

// K5c: write output from kept list.
__global__ void k_nms_gather(const float* __restrict__ boxes,
                             const unsigned* __restrict__ keptbuf,
                             float* __restrict__ out)
{
    int b = blockIdx.x;
    int t = threadIdx.x;
    unsigned kept = keptbuf[b * 304];
    if (t < POST_NMS) {
        size_t o = ((size_t)b * POST_NMS + t) * 5;
        float x1 = 0.f, y1 = 0.f, x2 = 0.f, y2 = 0.f;
        if (t < (int)kept) {
            unsigned idx = keptbuf[b * 304 + 1 + t];
            const float4 v = *(const float4*)(boxes + ((size_t)b * PRE_NMS + idx) * 4);
            x1 = v.x; y1 = v.y; x2 = v.z; y2 = v.w;
        }
        out[o + 0] = (float)b;
        out[o + 1] = x1; out[o + 2] = y1; out[o + 3] = x2; out[o + 4] = y2;
    }
}

// Fallback NMS (used only if ws_size is too small for the bitmask).
__global__ __launch_bounds__(1024) void k_nms_out(
    const float* __restrict__ boxes, float* __restrict__ out)
{
    __shared__ float bx1[PRE_NMS], by1[PRE_NMS], bx2[PRE_NMS], by2[PRE_NMS], bar[PRE_NMS];
    __shared__ unsigned rem[(PRE_NMS + 31) / 32];
    __shared__ int kept_idx[POST_NMS];

    int b = blockIdx.x;
    int t = threadIdx.x;

    for (int p = t; p < PRE_NMS; p += 1024) {
        size_t o = ((size_t)b * PRE_NMS + p) * 4;
        float x1 = boxes[o], y1 = boxes[o + 1], x2 = boxes[o + 2], y2 = boxes[o + 3];
        bx1[p] = x1; by1[p] = y1; bx2[p] = x2; by2[p] = y2;
        bar[p] = __fmul_rn(__fadd_rn(__fsub_rn(x2, x1), 1.0f),
                           __fadd_rn(__fsub_rn(y2, y1), 1.0f));
    }
    for (int p = t; p < (PRE_NMS + 31) / 32; p += 1024) rem[p] = 0u;
    __syncthreads();

    int kept = 0;
    for (int i = 0; i < PRE_NMS && kept < POST_NMS; ++i) {
        if (rem[i >> 5] & (1u << (i & 31))) continue;
        if (t == 0) kept_idx[kept] = i;
        float xi1 = bx1[i], yi1 = by1[i], xi2 = bx2[i], yi2 = by2[i], ai = bar[i];
        for (int j = i + 1 + t; j < PRE_NMS; j += 1024) {
            float xx1 = fmaxf(xi1, bx1[j]);
            float yy1 = fmaxf(yi1, by1[j]);
            float xx2 = fminf(xi2, bx2[j]);
            float yy2 = fminf(yi2, by2[j]);
            float iw = fmaxf(0.0f, __fadd_rn(__fsub_rn(xx2, xx1), 1.0f));
            float ih = fmaxf(0.0f, __fadd_rn(__fsub_rn(yy2, yy1), 1.0f));
            float inter = __fmul_rn(iw, ih);
            if (inter > 0.0f) {
                float uni = __fsub_rn(__fadd_rn(ai, bar[j]), inter);
                float iou = __fdiv_rn(inter, uni);
                if (iou > NMS_THRESH_F) atomicOr(&rem[j >> 5], 1u << (j & 31));
            }
        }
        ++kept;
        __syncthreads();
    }

    for (int k = t; k < POST_NMS; k += 1024) {
        size_t o = ((size_t)b * POST_NMS + k) * 5;
        out[o] = (float)b;
        if (k < kept) {
            int ii = kept_idx[k];
            out[o + 1] = bx1[ii]; out[o + 2] = by1[ii];
            out[o + 3] = bx2[ii]; out[o + 4] = by2[ii];
        } else {
            out[o + 1] = 0.0f; out[o + 2] = 0.0f; out[o + 3] = 0.0f; out[o + 4] = 0.0f;
        }
    }
}

extern "C" void kernel_launch(void* const* d_in, const int* in_sizes, int n_in,
                              void* d_out, int out_size, void* d_ws, size_t ws_size,
                              hipStream_t stream)
{
    const float* scores  = (const float*)d_in[0];
    const float* deltas  = (const float*)d_in[1];
    const float* im_info = (const float*)d_in[2];
    const float* anchors = (const float*)d_in[3];
    float* out = (float*)d_out;
    char* ws = (char*)d_ws;

    unsigned* bincnt           = (unsigned*)(ws + OFF_BINCNT);
    unsigned* cnt              = (unsigned*)(ws + OFF_CNT);
    unsigned* thresh           = cnt + 8;
    unsigned* binbase          = (unsigned*)(ws + OFF_BINBASE);
    unsigned* histg            = (unsigned*)(ws + OFF_HISTG);
    unsigned long long* seg    = (unsigned long long*)(ws + OFF_SEG);
    unsigned* keys             = (unsigned*)(ws + OFF_KEYS);
    float* boxes               = (float*)(ws + OFF_BOXES);
    unsigned* keptbuf          = (unsigned*)(ws + OFF_KEPT);
    unsigned long long* mask   = (unsigned long long*)(ws + OFF_MASK);

    // zero bin counters only
    hipMemsetAsync(ws, 0, OFF_CNT, stream);

    int total = B_NUM * N_ANCH;
    int blk = 256;
    k_decode<<<(total + blk - 1) / blk, blk, 0, stream>>>(
        scores, deltas, im_info, anchors, keys);
    k_hist_scan<<<B_NUM, 1024, 0, stream>>>(keys, histg, binbase, cnt, thresh);
    k_scatter<<<(total + blk - 1) / blk, blk, 0, stream>>>(
        keys, thresh, binbase, bincnt, seg);
    k_rank_decode<<<B_NUM * 128, 256, 0, stream>>>(
        seg, cnt, binbase, histg, deltas, im_info, anchors, boxes);

    if (ws_size >= (size_t)OFF_MASK + MASK_BYTES) {
        k_iou_mask<<<B_NUM * TRI_TILES, 64, 0, stream>>>(boxes, mask);
        k_nms_scan<<<B_NUM, 64, 0, stream>>>(mask, keptbuf);
        k_nms_gather<<<B_NUM, 320, 0, stream>>>(boxes, keptbuf, out);
    } else {
        k_nms_out<<<B_NUM, 1024, 0, stream>>>(boxes, out);
    }
}

// Round 8
// 302.128 us; speedup vs baseline: 4.7804x; 1.0737x over previous
//
#include <hip/hip_runtime.h>
#include <stdint.h>

#define FEAT_STRIDE_I 16
#define A_NUM 9
#define HH 128
#define WW 128
#define NPIX (HH * WW)            // 16384
#define N_ANCH (NPIX * A_NUM)     // 147456
#define B_NUM 8
#define PRE_NMS 6000
#define POST_NMS 300
#define NMS_THRESH_F 0.7f
#define MIN_SIZE_F 16.0f
#define NEG_INF_F -1e30f
#define NB2 32768                  // 15-bit bins (key>>17)
#define SEGCAP 16384

#define RT_TILES 94                // ceil(6000/64)
#define PT_TILES 2256              // sum_R ceil((94-R)/2): column-pair tiles
#define BQWORDS (RT_TILES * RT_TILES * 64)   // 565,504 qwords per batch

// swizzled LDS index: chunk walks (stride 32) become conflict-free
#define SW(i) ((i) + ((i) >> 5))

// ---- workspace layout (bytes) ----
#define OFF_BINCNT  0u             // 8*32768*4 = 1,048,576 (zeroed)
#define OFF_CNT     1048576u       // cnt[8] + thresh[8] (512 B)
#define OFF_BINBASE 1049088u       // 1,048,576
#define OFF_HISTG   2097664u       // 1,048,576
#define OFF_SEG     3146240u       // 8*16384*8 = 1,048,576
#define OFF_KEYS    4194816u       // 8*147456*4 = 4,718,592
#define OFF_BOXES   8913408u       // 8*6000*4*4 = 768,000
#define OFF_KEPT    9681408u       // 8*304*4 = 9,728
#define OFF_MASK    9691136u       // 8*565504*8 = 36,192,256 -> end 45,883,392
#define MASK_BYTES ((size_t)B_NUM * BQWORDS * 8)

__device__ __forceinline__ unsigned sortable_f32(float f) {
    unsigned u = __float_as_uint(f);
    return (u & 0x80000000u) ? ~u : (u | 0x80000000u);
}

// Decode one anchor's box exactly in the reference's op order.
__device__ __forceinline__ void decode_box(
    int b, int idx,
    const float* __restrict__ deltas, const float* __restrict__ im_info,
    const float* __restrict__ anchors,
    float& x1, float& y1, float& x2, float& y2, bool& valid)
{
    int a   = idx % A_NUM;
    int pix = idx / A_NUM;
    int w   = pix & (WW - 1);
    int h   = pix >> 7;

    float a0 = anchors[a * 4 + 0];
    float a1 = anchors[a * 4 + 1];
    float a2 = anchors[a * 4 + 2];
    float a3 = anchors[a * 4 + 3];

    float aw = __fadd_rn(__fsub_rn(a2, a0), 1.0f);
    float ah = __fadd_rn(__fsub_rn(a3, a1), 1.0f);
    float sx = (float)(w * FEAT_STRIDE_I);
    float sy = (float)(h * FEAT_STRIDE_I);
    float acx = __fadd_rn(__fadd_rn(sx, a0), __fmul_rn(0.5f, aw));
    float acy = __fadd_rn(__fadd_rn(sy, a1), __fmul_rn(0.5f, ah));

    size_t base = ((size_t)b * 36 + 4 * a) * NPIX + pix;
    float dx = deltas[base];
    float dy = deltas[base + NPIX];
    float dw = deltas[base + 2 * (size_t)NPIX];
    float dh = deltas[base + 3 * (size_t)NPIX];

    float pcx = __fadd_rn(__fmul_rn(dx, aw), acx);
    float pcy = __fadd_rn(__fmul_rn(dy, ah), acy);
    float pw  = __fmul_rn(expf(dw), aw);
    float ph  = __fmul_rn(expf(dh), ah);

    float hx = __fmul_rn(0.5f, pw);
    float hy = __fmul_rn(0.5f, ph);
    x1 = __fsub_rn(pcx, hx);
    y1 = __fsub_rn(pcy, hy);
    x2 = __fadd_rn(pcx, hx);
    y2 = __fadd_rn(pcy, hy);

    float im_h = im_info[b * 3 + 0];
    float im_w = im_info[b * 3 + 1];
    float sc   = im_info[b * 3 + 2];
    float wmax = __fsub_rn(im_w, 1.0f);
    float hmax = __fsub_rn(im_h, 1.0f);

    x1 = fminf(fmaxf(x1, 0.0f), wmax);
    y1 = fminf(fmaxf(y1, 0.0f), hmax);
    x2 = fminf(fmaxf(x2, 0.0f), wmax);
    y2 = fminf(fmaxf(y2, 0.0f), hmax);

    float min_sz = __fmul_rn(MIN_SIZE_F, sc);
    valid = (__fadd_rn(__fsub_rn(x2, x1), 1.0f) >= min_sz) &&
            (__fadd_rn(__fsub_rn(y2, y1), 1.0f) >= min_sz);
}

// K1: decode + masked score -> sortable key. Pure streaming, no atomics.
__global__ void k_decode(
    const float* __restrict__ scores, const float* __restrict__ deltas,
    const float* __restrict__ im_info, const float* __restrict__ anchors,
    unsigned* __restrict__ keys)
{
    int gt = blockIdx.x * blockDim.x + threadIdx.x;
    if (gt >= B_NUM * N_ANCH) return;
    int pix  = gt & (NPIX - 1);
    int rest = gt >> 14;
    int a = rest % A_NUM;
    int b = rest / A_NUM;
    int idx = pix * A_NUM + a;

    float x1, y1, x2, y2; bool valid;
    decode_box(b, idx, deltas, im_info, anchors, x1, y1, x2, y2, valid);

    float s = scores[((size_t)b * 18 + 9 + a) * NPIX + pix];
    if (!valid) s = NEG_INF_F;
    keys[gt] = sortable_f32(s);
}

// K2: one block per batch. Full 32768-bin histogram in LDS (no global
// atomics), suffix-scan in place, write hist/binbase/thresh/cnt.
__global__ __launch_bounds__(1024) void k_hist_scan(
    const unsigned* __restrict__ keys, unsigned* __restrict__ histg,
    unsigned* __restrict__ binbase, unsigned* __restrict__ cnt,
    unsigned* __restrict__ thresh)
{
    __shared__ unsigned lds[SW(NB2 - 1) + 2];   // 33792 words, swizzled
    __shared__ unsigned csum[1024];
    __shared__ unsigned sT;

    int b = blockIdx.x;
    int t = threadIdx.x;
    if (t == 0) sT = 0;
    for (int i = t; i < SW(NB2 - 1) + 2; i += 1024) lds[i] = 0u;
    __syncthreads();

    // build histogram via LDS atomics
    const unsigned* kb = keys + (size_t)b * N_ANCH;
    for (int i = t; i < N_ANCH; i += 1024)
        atomicAdd(&lds[SW(kb[i] >> 17)], 1u);
    __syncthreads();

    // write hist to global (coalesced)
    unsigned* hg = histg + (size_t)b * NB2;
    for (int i = t; i < NB2; i += 1024) hg[i] = lds[SW(i)];

    // per-thread chunk sum (32 bins, swizzle -> conflict-free)
    int base = t * 32;
    unsigned s = 0;
    for (int u = 0; u < 32; ++u) s += lds[SW(base + u)];
    csum[t] = s;
    __syncthreads();

    // inclusive suffix scan (Hillis-Steele)
    for (int off = 1; off < 1024; off <<= 1) {
        unsigned v = (t + off < 1024) ? csum[t + off] : 0u;
        __syncthreads();
        csum[t] += v;
        __syncthreads();
    }
    unsigned before = csum[t] - s;   // keys in strictly higher chunks

    // find threshold candidate within chunk
    unsigned acc = before;
    for (int bin = base + 31; bin >= base; --bin) {
        unsigned hh = lds[SW(bin)];
        if (acc + hh >= PRE_NMS) { atomicMax(&sT, (unsigned)bin); break; }
        acc += hh;
    }
    __syncthreads();
    unsigned T = sT;

    // walk chunk high->low: overwrite LDS hist with binbase; catch cnt at T
    acc = before;
    for (int bin = base + 31; bin >= base; --bin) {
        unsigned hh = lds[SW(bin)];
        if ((unsigned)bin == T) cnt[b] = acc + hh;
        lds[SW(bin)] = acc;
        acc += hh;
    }
    if (t == 0) thresh[b] = T;
    __syncthreads();

    // write binbase (coalesced)
    unsigned* bb = binbase + (size_t)b * NB2;
    for (int i = t; i < NB2; i += 1024) bb[i] = lds[SW(i)];
}

// K3: scatter passing keys (bin >= T) into bin-segmented array.
__global__ void k_scatter(
    const unsigned* __restrict__ keys, const unsigned* __restrict__ thresh,
    const unsigned* __restrict__ binbase, unsigned* __restrict__ bincnt,
    unsigned long long* __restrict__ seg)
{
    int gt = blockIdx.x * blockDim.x + threadIdx.x;
    int pix  = gt & (NPIX - 1);
    int rest = gt >> 14;
    int a = rest % A_NUM;
    int b = rest / A_NUM;

    unsigned key = keys[gt];
    unsigned bin = key >> 17;
    if (bin >= thresh[b]) {
        unsigned slot = atomicAdd(&bincnt[(size_t)b * NB2 + bin], 1u);
        unsigned pos = binbase[(size_t)b * NB2 + bin] + slot;
        if (pos < SEGCAP) {
            unsigned idx = (unsigned)(pix * A_NUM + a);
            seg[(size_t)b * SEGCAP + pos] =
                ((unsigned long long)key << 32) | (unsigned long long)(0xFFFFFFFFu - idx);
        }
    }
}

// K4: exact rank within own bin segment + binbase = global rank; decode box
// straight into its sorted slot.
__global__ __launch_bounds__(256) void k_rank_decode(
    const unsigned long long* __restrict__ seg, const unsigned* __restrict__ cnt,
    const unsigned* __restrict__ binbase, const unsigned* __restrict__ histg,
    const float* __restrict__ deltas, const float* __restrict__ im_info,
    const float* __restrict__ anchors, float* __restrict__ boxes)
{
    int b = blockIdx.x >> 7;
    int p = ((blockIdx.x & 127) << 8) + threadIdx.x;
    unsigned n = cnt[b];
    if (n > SEGCAP) n = SEGCAP;
    if (p >= (int)n) return;

    const unsigned long long* S = seg + (size_t)b * SEGCAP;
    unsigned long long key = S[p];
    unsigned bin = (unsigned)(key >> 49);
    unsigned base = binbase[(size_t)b * NB2 + bin];
    unsigned end = base + histg[(size_t)b * NB2 + bin];
    if (end > SEGCAP) end = SEGCAP;

    unsigned rank = base;
    for (unsigned q = base; q < end; ++q)
        rank += (S[q] > key) ? 1u : 0u;

    if (rank < PRE_NMS) {
        int idx = (int)(0xFFFFFFFFu - (unsigned)(key & 0xFFFFFFFFull));
        float x1, y1, x2, y2; bool v;
        decode_box(b, idx, deltas, im_info, anchors, x1, y1, x2, y2, v);
        float4 o = make_float4(x1, y1, x2, y2);
        *(float4*)(boxes + ((size_t)b * PRE_NMS + rank) * 4) = o;
    }
}

// One row of a 64x64 suppression block: inter/uni in the reference's exact
// op order; division eliminated except in the proven +-6e-7*uni band
// (round-6 proof; validated absmax=0). Returns the 64-bit suppress mask.
__device__ __forceinline__ unsigned long long iou_row(
    float4 bi, float ia, float jx1, float jy1, float jx2, float jy2, float ja)
{
    float xx1 = fmaxf(bi.x, jx1);
    float yy1 = fmaxf(bi.y, jy1);
    float xx2 = fminf(bi.z, jx2);
    float yy2 = fminf(bi.w, jy2);
    float iw = fmaxf(0.0f, __fadd_rn(__fsub_rn(xx2, xx1), 1.0f));
    float ih = fmaxf(0.0f, __fadd_rn(__fsub_rn(yy2, yy1), 1.0f));
    float inter = __fmul_rn(iw, ih);
    float uni = __fsub_rn(__fadd_rn(ia, ja), inter);
    float diff = __fsub_rn(inter, __fmul_rn(NMS_THRESH_F, uni));
    unsigned long long sup = __ballot(diff > 0.0f);
    unsigned long long band = __ballot(fabsf(diff) <= __fmul_rn(6e-7f, uni));
    if (band) {   // rare; wave-uniform branch
        unsigned long long supd = __ballot(__fdiv_rn(inter, uni) > NMS_THRESH_F);
        sup = (sup & ~band) | (supd & band);
    }
    return sup;
}

// K5a: upper-triangular IoU suppression bitmask, blocked layout
// mask[b][R][C][64] (u64). One wave per (batch, row-tile, column-PAIR):
// LDS row reads + accumulate amortize over 2 column tiles. Redundant
// predicates removed: inter>0 (inter=0 => diff=-0.7*uni<0, band can't
// trigger), j>=PRE_NMS (degenerate box (0,0,-1,-1) => iw=0 => no sup),
// j>i (scalar mask (~1<<ri) applied only on the 94 diagonal tiles).
__global__ __launch_bounds__(64) void k_iou_mask(
    const float* __restrict__ boxes, unsigned long long* __restrict__ mask)
{
    int bid = blockIdx.x;
    int b = bid / PT_TILES;
    int t = bid - b * PT_TILES;
    int R = 0;
    while (t >= ((95 - R) >> 1)) { t -= (95 - R) >> 1; ++R; }   // scalar, <=94 iters
    int C1 = R + 2 * t;
    int C2 = C1 + 1;

    int lane = threadIdx.x;
    const float* Bb = boxes + (size_t)b * PRE_NMS * 4;

    // column boxes (degenerate for j >= PRE_NMS or C out of range)
    float j1x1 = 0.f, j1y1 = 0.f, j1x2 = -1.f, j1y2 = -1.f;
    float j2x1 = 0.f, j2y1 = 0.f, j2x2 = -1.f, j2y2 = -1.f;
    int j1 = C1 * 64 + lane;
    int j2 = C2 * 64 + lane;
    if (j1 < PRE_NMS) {
        float4 v = *(const float4*)(Bb + 4 * (size_t)j1);
        j1x1 = v.x; j1y1 = v.y; j1x2 = v.z; j1y2 = v.w;
    }
    if (C2 < RT_TILES && j2 < PRE_NMS) {
        float4 v = *(const float4*)(Bb + 4 * (size_t)j2);
        j2x1 = v.x; j2y1 = v.y; j2x2 = v.z; j2y2 = v.w;
    }
    float j1a = __fmul_rn(__fadd_rn(__fsub_rn(j1x2, j1x1), 1.0f),
                          __fadd_rn(__fsub_rn(j1y2, j1y1), 1.0f));
    float j2a = __fmul_rn(__fadd_rn(__fsub_rn(j2x2, j2x1), 1.0f),
                          __fadd_rn(__fsub_rn(j2y2, j2y1), 1.0f));

    // row boxes -> LDS (degenerate beyond PRE_NMS)
    __shared__ float4 rb4[64];
    __shared__ float rba[64];
    int il = R * 64 + lane;
    float4 rv = make_float4(0.f, 0.f, -1.f, -1.f);
    if (il < PRE_NMS) rv = *(const float4*)(Bb + 4 * (size_t)il);
    rb4[lane] = rv;
    rba[lane] = __fmul_rn(__fadd_rn(__fsub_rn(rv.z, rv.x), 1.0f),
                          __fadd_rn(__fsub_rn(rv.w, rv.y), 1.0f));
    __syncthreads();

    unsigned long long w1 = 0ULL, w2 = 0ULL;
    if (C1 == R) {
        #pragma unroll 4
        for (int ri = 0; ri < 64; ++ri) {
            float4 bi = rb4[ri];
            float ia = rba[ri];
            unsigned long long s1 = iou_row(bi, ia, j1x1, j1y1, j1x2, j1y2, j1a)
                                    & (0xFFFFFFFFFFFFFFFEull << ri);
            unsigned long long s2 = iou_row(bi, ia, j2x1, j2y1, j2x2, j2y2, j2a);
            w1 = (lane == ri) ? s1 : w1;
            w2 = (lane == ri) ? s2 : w2;
        }
    } else {
        #pragma unroll 4
        for (int ri = 0; ri < 64; ++ri) {
            float4 bi = rb4[ri];
            float ia = rba[ri];
            unsigned long long s1 = iou_row(bi, ia, j1x1, j1y1, j1x2, j1y2, j1a);
            unsigned long long s2 = iou_row(bi, ia, j2x1, j2y1, j2x2, j2y2, j2a);
            w1 = (lane == ri) ? s1 : w1;
            w2 = (lane == ri) ? s2 : w2;
        }
    }

    unsigned long long* Mb = mask + (size_t)b * BQWORDS;
    Mb[(size_t)(R * RT_TILES + C1) * 64 + lane] = w1;
    if (C2 < RT_TILES)
        Mb[(size_t)(R * RT_TILES + C2) * 64 + lane] = w2;
}

// K5b: serial greedy scan over the blocked bitmask, one wave per batch.
// Row i's 94 qwords live at M[(R*94+C)*64 + r], C = 0..93 (stride 512B).
// Lane l covers C=l and (l<30) C=64+l. 8-deep unconditional prefetch.
__global__ __launch_bounds__(64) void k_nms_scan(
    const unsigned long long* __restrict__ mask, unsigned* __restrict__ keptbuf)
{
    const int b = blockIdx.x;
    const int l = threadIdx.x;
    __shared__ unsigned long long supp[RT_TILES];
    __shared__ int klist[POST_NMS];
    supp[l] = 0ULL;
    if (l < RT_TILES - 64) supp[l + 64] = 0ULL;
    __syncthreads();

    const unsigned long long* __restrict__ M = mask + (size_t)b * BQWORDS;
    int kept = 0;
    unsigned long long curw = 0; int curwi = -1;

#define LOADROW(p0, p1, i) { \
        int _i = ((i) < PRE_NMS) ? (i) : (PRE_NMS - 1); \
        const unsigned long long* _r = M + (size_t)((_i >> 6) * RT_TILES) * 64 + (_i & 63); \
        p0 = _r[l * 64]; \
        p1 = (l < RT_TILES - 64) ? _r[(64 + l) * 64] : 0ULL; }

#define STEP(i, p0, p1) { \
        if (kept < POST_NMS) { \
            int _wi = (i) >> 6; \
            if (_wi != curwi) { curw = supp[_wi]; curwi = _wi; } \
            if (!((curw >> ((i) & 63)) & 1ULL)) { \
                if (l == 0) klist[kept] = (i); \
                supp[l] |= p0; \
                if (l < RT_TILES - 64) supp[l + 64] |= p1; \
                ++kept; curwi = -1; \
            } \
        } }

    unsigned long long a0, a1, c0, c1, d0, d1, e0, e1;
    unsigned long long f0, f1, g0, g1, h0, h1, q0, q1;
    LOADROW(a0, a1, 0) LOADROW(c0, c1, 1)
    LOADROW(d0, d1, 2) LOADROW(e0, e1, 3)
    LOADROW(f0, f1, 4) LOADROW(g0, g1, 5)
    LOADROW(h0, h1, 6) LOADROW(q0, q1, 7)

    for (int i = 0; i < PRE_NMS && kept < POST_NMS; i += 8) {
        STEP(i + 0, a0, a1) LOADROW(a0, a1, i + 8)
        STEP(i + 1, c0, c1) LOADROW(c0, c1, i + 9)
        STEP(i + 2, d0, d1) LOADROW(d0, d1, i + 10)
        STEP(i + 3, e0, e1) LOADROW(e0, e1, i + 11)
        STEP(i + 4, f0, f1) LOADROW(f0, f1, i + 12)
        STEP(i + 5, g0, g1) LOADROW(g0, g1, i + 13)
        STEP(i + 6, h0, h1) LOADROW(h0, h1, i + 14)
        STEP(i + 7, q0, q1) LOADROW(q0, q1, i + 15)
    }
    __syncthreads();
    if (l == 0) keptbuf[b * 304] = (unsigned)kept;
    for (int k = l; k < POST_NMS; k += 64)
        keptbuf[b * 304 + 1 + k] = (k < (int)kept) ? (unsigned)klist[k] : 0u;
#undef LOADROW
#undef STEP
}

// K5c: write output from kept list.
__global__ void k_nms_gather(const float* __restrict__ boxes,
                             const unsigned* __restrict__ keptbuf,
                             float* __restrict__ out)
{
    int b = blockIdx.x;
    int t = threadIdx.x;
    unsigned kept = keptbuf[b * 304];
    if (t < POST_NMS) {
        size_t o = ((size_t)b * POST_NMS + t) * 5;
        float x1 = 0.f, y1 = 0.f, x2 = 0.f, y2 = 0.f;
        if (t < (int)kept) {
            unsigned idx = keptbuf[b * 304 + 1 + t];
            const float4 v = *(const float4*)(boxes + ((size_t)b * PRE_NMS + idx) * 4);
            x1 = v.x; y1 = v.y; x2 = v.z; y2 = v.w;
        }
        out[o + 0] = (float)b;
        out[o + 1] = x1; out[o + 2] = y1; out[o + 3] = x2; out[o + 4] = y2;
    }
}

// Fallback NMS (used only if ws_size is too small for the bitmask).
__global__ __launch_bounds__(1024) void k_nms_out(
    const float* __restrict__ boxes, float* __restrict__ out)
{
    __shared__ float bx1[PRE_NMS], by1[PRE_NMS], bx2[PRE_NMS], by2[PRE_NMS], bar[PRE_NMS];
    __shared__ unsigned rem[(PRE_NMS + 31) / 32];
    __shared__ int kept_idx[POST_NMS];

    int b = blockIdx.x;
    int t = threadIdx.x;

    for (int p = t; p < PRE_NMS; p += 1024) {
        size_t o = ((size_t)b * PRE_NMS + p) * 4;
        float x1 = boxes[o], y1 = boxes[o + 1], x2 = boxes[o + 2], y2 = boxes[o + 3];
        bx1[p] = x1; by1[p] = y1; bx2[p] = x2; by2[p] = y2;
        bar[p] = __fmul_rn(__fadd_rn(__fsub_rn(x2, x1), 1.0f),
                           __fadd_rn(__fsub_rn(y2, y1), 1.0f));
    }
    for (int p = t; p < (PRE_NMS + 31) / 32; p += 1024) rem[p] = 0u;
    __syncthreads();

    int kept = 0;
    for (int i = 0; i < PRE_NMS && kept < POST_NMS; ++i) {
        if (rem[i >> 5] & (1u << (i & 31))) continue;
        if (t == 0) kept_idx[kept] = i;
        float xi1 = bx1[i], yi1 = by1[i], xi2 = bx2[i], yi2 = by2[i], ai = bar[i];
        for (int j = i + 1 + t; j < PRE_NMS; j += 1024) {
            float xx1 = fmaxf(xi1, bx1[j]);
            float yy1 = fmaxf(yi1, by1[j]);
            float xx2 = fminf(xi2, bx2[j]);
            float yy2 = fminf(yi2, by2[j]);
            float iw = fmaxf(0.0f, __fadd_rn(__fsub_rn(xx2, xx1), 1.0f));
            float ih = fmaxf(0.0f, __fadd_rn(__fsub_rn(yy2, yy1), 1.0f));
            float inter = __fmul_rn(iw, ih);
            if (inter > 0.0f) {
                float uni = __fsub_rn(__fadd_rn(ai, bar[j]), inter);
                float iou = __fdiv_rn(inter, uni);
                if (iou > NMS_THRESH_F) atomicOr(&rem[j >> 5], 1u << (j & 31));
            }
        }
        ++kept;
        __syncthreads();
    }

    for (int k = t; k < POST_NMS; k += 1024) {
        size_t o = ((size_t)b * POST_NMS + k) * 5;
        out[o] = (float)b;
        if (k < kept) {
            int ii = kept_idx[k];
            out[o + 1] = bx1[ii]; out[o + 2] = by1[ii];
            out[o + 3] = bx2[ii]; out[o + 4] = by2[ii];
        } else {
            out[o + 1] = 0.0f; out[o + 2] = 0.0f; out[o + 3] = 0.0f; out[o + 4] = 0.0f;
        }
    }
}

extern "C" void kernel_launch(void* const* d_in, const int* in_sizes, int n_in,
                              void* d_out, int out_size, void* d_ws, size_t ws_size,
                              hipStream_t stream)
{
    const float* scores  = (const float*)d_in[0];
    const float* deltas  = (const float*)d_in[1];
    const float* im_info = (const float*)d_in[2];
    const float* anchors = (const float*)d_in[3];
    float* out = (float*)d_out;
    char* ws = (char*)d_ws;

    unsigned* bincnt           = (unsigned*)(ws + OFF_BINCNT);
    unsigned* cnt              = (unsigned*)(ws + OFF_CNT);
    unsigned* thresh           = cnt + 8;
    unsigned* binbase          = (unsigned*)(ws + OFF_BINBASE);
    unsigned* histg            = (unsigned*)(ws + OFF_HISTG);
    unsigned long long* seg    = (unsigned long long*)(ws + OFF_SEG);
    unsigned* keys             = (unsigned*)(ws + OFF_KEYS);
    float* boxes               = (float*)(ws + OFF_BOXES);
    unsigned* keptbuf          = (unsigned*)(ws + OFF_KEPT);
    unsigned long long* mask   = (unsigned long long*)(ws + OFF_MASK);

    // zero bin counters only
    hipMemsetAsync(ws, 0, OFF_CNT, stream);

    int total = B_NUM * N_ANCH;
    int blk = 256;
    k_decode<<<(total + blk - 1) / blk, blk, 0, stream>>>(
        scores, deltas, im_info, anchors, keys);
    k_hist_scan<<<B_NUM, 1024, 0, stream>>>(keys, histg, binbase, cnt, thresh);
    k_scatter<<<(total + blk - 1) / blk, blk, 0, stream>>>(
        keys, thresh, binbase, bincnt, seg);
    k_rank_decode<<<B_NUM * 128, 256, 0, stream>>>(
        seg, cnt, binbase, histg, deltas, im_info, anchors, boxes);

    if (ws_size >= (size_t)OFF_MASK + MASK_BYTES) {
        k_iou_mask<<<B_NUM * PT_TILES, 64, 0, stream>>>(boxes, mask);
        k_nms_scan<<<B_NUM, 64, 0, stream>>>(mask, keptbuf);
        k_nms_gather<<<B_NUM, 320, 0, stream>>>(boxes, keptbuf, out);
    } else {
        k_nms_out<<<B_NUM, 1024, 0, stream>>>(boxes, out);
    }
}